// Round 1
// baseline (2982.160 us; speedup 1.0000x reference)
//
#include <hip/hip_runtime.h>

// GridGNN: 2x GCNConv(64->64) + ReLU, global_mean_pool, Linear(64->3), softmax.
// N=100000 nodes, E=1600000 edges, G=64 graphs, F=64 feats, fp32 throughout.

#define FDIM 64
#define NGRAPH 64

// ---- degree count: cnt[dst]++ ----
__global__ void k_count(const int* __restrict__ dst, int* __restrict__ cnt, int nE) {
    int i = blockIdx.x * blockDim.x + threadIdx.x;
    int stride = gridDim.x * blockDim.x;
    for (; i < nE; i += stride) atomicAdd(&cnt[dst[i]], 1);
}

// ---- dinv[i] = rsqrt(1 + indeg[i]) ----
__global__ void k_dinv(const int* __restrict__ cnt, float* __restrict__ dinv, int nN) {
    int i = blockIdx.x * blockDim.x + threadIdx.x;
    int stride = gridDim.x * blockDim.x;
    for (; i < nN; i += stride) dinv[i] = rsqrtf(1.0f + (float)cnt[i]);
}

// ---- Out[r][c] = sum_k X[r][k] * W[k][c], W is 64x64 row-major ----
__global__ void k_gemm64(const float* __restrict__ X, const float* __restrict__ W,
                         float* __restrict__ Out, int nRows) {
    __shared__ float Ws[64][64];
    __shared__ float xs[4][64];
    int tid = threadIdx.x;
    for (int i = tid; i < 64 * 64; i += 256) Ws[i >> 6][i & 63] = W[i];
    __syncthreads();
    int c = tid & 63, rl = tid >> 6;
    for (int r0 = blockIdx.x * 4; r0 < nRows; r0 += gridDim.x * 4) {
        int r = r0 + rl;
        if (r < nRows) xs[rl][c] = X[(size_t)r * 64 + c];
        __syncthreads();
        if (r < nRows) {
            float acc = 0.f;
#pragma unroll
            for (int k = 0; k < 64; ++k) acc = fmaf(xs[rl][k], Ws[k][c], acc);
            Out[(size_t)r * 64 + c] = acc;
        }
        __syncthreads();
    }
}

// ---- agg[dst] += h[src] * dinv[src]*dinv[dst]; 16 lanes per edge, float4 ----
__global__ void k_scatter(const int* __restrict__ src, const int* __restrict__ dst,
                          const float* __restrict__ dinv, const float* __restrict__ H,
                          float* __restrict__ agg, int nE) {
    int lane = threadIdx.x & 15;
    int eg = (blockIdx.x * blockDim.x + threadIdx.x) >> 4;
    int stride = (gridDim.x * blockDim.x) >> 4;
    for (int e = eg; e < nE; e += stride) {
        int s = src[e], d = dst[e];
        float coef = dinv[s] * dinv[d];
        const float4 v = *reinterpret_cast<const float4*>(H + (size_t)s * 64 + lane * 4);
        float* p = agg + (size_t)d * 64 + lane * 4;
        unsafeAtomicAdd(p + 0, v.x * coef);
        unsafeAtomicAdd(p + 1, v.y * coef);
        unsafeAtomicAdd(p + 2, v.z * coef);
        unsafeAtomicAdd(p + 3, v.w * coef);
    }
}

// ---- Y = (relu?)( agg + H*dinv^2 + b ); element-parallel float4 (may alias agg==Y) ----
__global__ void k_combine(const float* agg, const float* __restrict__ H,
                          const float* __restrict__ dinv, const float* __restrict__ b,
                          float* Y, int nN, int relu) {
    int i = blockIdx.x * blockDim.x + threadIdx.x;  // one float4 per thread
    int total = nN * 16;
    int stride = gridDim.x * blockDim.x;
    for (; i < total; i += stride) {
        int node = i >> 4;
        int q = i & 15;
        float di = dinv[node];
        float sc = di * di;
        float4 a = ((const float4*)agg)[i];
        float4 h = ((const float4*)H)[i];
        float4 bb = ((const float4*)b)[q];
        float x0 = a.x + h.x * sc + bb.x;
        float x1 = a.y + h.y * sc + bb.y;
        float x2 = a.z + h.z * sc + bb.z;
        float x3 = a.w + h.w * sc + bb.w;
        if (relu) {
            x0 = fmaxf(x0, 0.f); x1 = fmaxf(x1, 0.f);
            x2 = fmaxf(x2, 0.f); x3 = fmaxf(x3, 0.f);
        }
        ((float4*)Y)[i] = make_float4(x0, x1, x2, x3);
    }
}

// ---- pooled sums + counts; batch is sorted, so flush on graph-id change ----
__global__ void k_pool(const float* __restrict__ Y, const int* __restrict__ batch,
                       float* __restrict__ gsum, float* __restrict__ gcnt, int nN) {
    const int CH = 512;
    int n0 = blockIdx.x * CH;
    int f = threadIdx.x & 63, rl = threadIdx.x >> 6;
    int nend = n0 + CH; if (nend > nN) nend = nN;
    int curg = -1;
    float acc = 0.f, cacc = 0.f;
    for (int n = n0 + rl; n < nend; n += 4) {
        int g = batch[n];
        if (g != curg) {
            if (curg >= 0) {
                unsafeAtomicAdd(&gsum[curg * 64 + f], acc);
                if (f == 0) unsafeAtomicAdd(&gcnt[curg], cacc);
            }
            curg = g; acc = 0.f; cacc = 0.f;
        }
        acc += Y[(size_t)n * 64 + f];
        cacc += 1.f;
    }
    if (curg >= 0) {
        unsafeAtomicAdd(&gsum[curg * 64 + f], acc);
        if (f == 0) unsafeAtomicAdd(&gcnt[curg], cacc);
    }
}

// ---- head: mean -> @Wl + bl -> softmax(3) ----
__global__ void k_head(const float* __restrict__ gsum, const float* __restrict__ gcnt,
                       const float* __restrict__ Wl, const float* __restrict__ bl,
                       float* __restrict__ out) {
    int g = threadIdx.x;
    if (g >= NGRAPH) return;
    float inv = 1.0f / fmaxf(gcnt[g], 1.0f);
    float l0 = bl[0], l1 = bl[1], l2 = bl[2];
#pragma unroll
    for (int k = 0; k < 64; ++k) {
        float m = gsum[g * 64 + k] * inv;
        l0 = fmaf(m, Wl[k * 3 + 0], l0);
        l1 = fmaf(m, Wl[k * 3 + 1], l1);
        l2 = fmaf(m, Wl[k * 3 + 2], l2);
    }
    float mx = fmaxf(l0, fmaxf(l1, l2));
    float e0 = expf(l0 - mx), e1 = expf(l1 - mx), e2 = expf(l2 - mx);
    float s = e0 + e1 + e2;
    out[g * 3 + 0] = e0 / s;
    out[g * 3 + 1] = e1 / s;
    out[g * 3 + 2] = e2 / s;
}

extern "C" void kernel_launch(void* const* d_in, const int* in_sizes, int n_in,
                              void* d_out, int out_size, void* d_ws, size_t ws_size,
                              hipStream_t stream) {
    const float* x     = (const float*)d_in[0];
    const int*   ei    = (const int*)d_in[1];
    const int*   batch = (const int*)d_in[2];
    const float* W1    = (const float*)d_in[3];
    const float* b1    = (const float*)d_in[4];
    const float* W2    = (const float*)d_in[5];
    const float* b2    = (const float*)d_in[6];
    const float* Wl    = (const float*)d_in[7];
    const float* bl    = (const float*)d_in[8];
    float* out = (float*)d_out;

    int nN = in_sizes[2];
    int nE = in_sizes[1] / 2;
    const int* srcp = ei;
    const int* dstp = ei + nE;

    char* ws = (char*)d_ws;
    size_t off = 0;
    auto alloc = [&](size_t bytes) -> void* {
        void* p = ws + off;
        off += (bytes + 255) & ~(size_t)255;
        return p;
    };
    float* dinv = (float*)alloc((size_t)nN * 4);
    int*   cnt  = (int*)alloc((size_t)nN * 4);
    float* bufA = (float*)alloc((size_t)nN * 64 * 4);
    float* bufB = (float*)alloc((size_t)nN * 64 * 4);
    float* gsum = (float*)alloc(NGRAPH * 64 * 4);
    float* gcnt = (float*)alloc(NGRAPH * 4);

    hipMemsetAsync(cnt, 0, (size_t)nN * 4, stream);
    hipMemsetAsync(bufB, 0, (size_t)nN * 64 * 4, stream);
    hipMemsetAsync(gsum, 0, NGRAPH * 64 * 4, stream);
    hipMemsetAsync(gcnt, 0, NGRAPH * 4, stream);

    // degree + norm
    k_count<<<1024, 256, 0, stream>>>(dstp, cnt, nE);
    k_dinv<<<(nN + 255) / 256, 256, 0, stream>>>(cnt, dinv, nN);

    // layer 1: h1 = x@W1 -> bufA ; agg -> bufB ; y1 = relu(combine) -> bufB
    k_gemm64<<<1024, 256, 0, stream>>>(x, W1, bufA, nN);
    k_scatter<<<2048, 256, 0, stream>>>(srcp, dstp, dinv, bufA, bufB, nE);
    k_combine<<<2048, 256, 0, stream>>>(bufB, bufA, dinv, b1, bufB, nN, 1);

    // layer 2: h2 = y1@W2 -> bufA ; zero bufB ; agg -> bufB ; y2 = combine -> bufB
    k_gemm64<<<1024, 256, 0, stream>>>(bufB, W2, bufA, nN);
    hipMemsetAsync(bufB, 0, (size_t)nN * 64 * 4, stream);
    k_scatter<<<2048, 256, 0, stream>>>(srcp, dstp, dinv, bufA, bufB, nE);
    k_combine<<<2048, 256, 0, stream>>>(bufB, bufA, dinv, b2, bufB, nN, 0);

    // pool + head
    k_pool<<<(nN + 511) / 512, 256, 0, stream>>>(bufB, batch, gsum, gcnt, nN);
    k_head<<<1, 64, 0, stream>>>(gsum, gcnt, Wl, bl, out);
}

// Round 2
// 454.413 us; speedup vs baseline: 6.5627x; 6.5627x over previous
//
#include <hip/hip_runtime.h>

// GridGNN: 2x GCNConv(64->64) + ReLU, global_mean_pool, Linear(64->3), softmax.
// N=100000 nodes, E=1600000 edges, G=64 graphs, F=64 feats, fp32 throughout.
// R1: replace fp32 atomic scatter (1.6GB HBM write-through, 2x1367us) with
// CSR build (int atomics only) + fused gather/combine per dst node.

#define FDIM 64
#define NGRAPH 64

#define SCAN_T 256
#define SCAN_E 16
#define SCAN_B (SCAN_T * SCAN_E)  // 4096 elems per scan block

// ---- degree count: cnt[dst]++ ----
__global__ void k_count(const int* __restrict__ dst, int* __restrict__ cnt, int nE) {
    int i = blockIdx.x * blockDim.x + threadIdx.x;
    int stride = gridDim.x * blockDim.x;
    for (; i < nE; i += stride) atomicAdd(&cnt[dst[i]], 1);
}

// ---- dinv[i] = rsqrt(1 + indeg[i]) ----
__global__ void k_dinv(const int* __restrict__ cnt, float* __restrict__ dinv, int nN) {
    int i = blockIdx.x * blockDim.x + threadIdx.x;
    int stride = gridDim.x * blockDim.x;
    for (; i < nN; i += stride) dinv[i] = rsqrtf(1.0f + (float)cnt[i]);
}

// ---- scan stage A: per-block exclusive scan of cnt -> rowptr, block totals ----
__global__ void k_scanA(const int* __restrict__ cnt, int* __restrict__ rowptr,
                        int* __restrict__ bsums, int nN) {
    __shared__ int sh[SCAN_T];
    int b = blockIdx.x, tid = threadIdx.x;
    int base = b * SCAN_B + tid * SCAN_E;
    int v[SCAN_E];
    int s = 0;
#pragma unroll
    for (int j = 0; j < SCAN_E; ++j) {
        int idx = base + j;
        int c = (idx < nN) ? cnt[idx] : 0;
        v[j] = s;
        s += c;
    }
    sh[tid] = s;
    __syncthreads();
    // Hillis-Steele inclusive scan over thread partials
    for (int off = 1; off < SCAN_T; off <<= 1) {
        int t = (tid >= off) ? sh[tid - off] : 0;
        __syncthreads();
        sh[tid] += t;
        __syncthreads();
    }
    int excl = (tid == 0) ? 0 : sh[tid - 1];
    if (tid == SCAN_T - 1) bsums[b] = sh[tid];
#pragma unroll
    for (int j = 0; j < SCAN_E; ++j) {
        int idx = base + j;
        if (idx < nN) rowptr[idx] = excl + v[j];
    }
}

// ---- scan stage B: serial exclusive scan of block sums (nB <= 64) ----
__global__ void k_scanB(int* __restrict__ bsums, int* __restrict__ rowptr, int nB, int nN) {
    int run = 0;
    for (int i = 0; i < nB; ++i) {
        int t = bsums[i];
        bsums[i] = run;
        run += t;
    }
    rowptr[nN] = run;  // == nE
}

// ---- scan stage C: add block offsets; init cursor = rowptr ----
__global__ void k_scanC(int* __restrict__ rowptr, const int* __restrict__ bsums,
                        int* __restrict__ cursor, int nN) {
    int b = blockIdx.x, tid = threadIdx.x;
    int add = bsums[b];
    int base = b * SCAN_B;
#pragma unroll
    for (int j = 0; j < SCAN_E; ++j) {
        int idx = base + tid + j * SCAN_T;
        if (idx < nN) {
            int r = rowptr[idx] + add;
            rowptr[idx] = r;
            cursor[idx] = r;
        }
    }
}

// ---- bucket edges by dst: erec[pos] = {src, coef} ----
__global__ void k_bucket(const int* __restrict__ src, const int* __restrict__ dst,
                         const float* __restrict__ dinv, int* __restrict__ cursor,
                         int2* __restrict__ erec, int nE) {
    int i = blockIdx.x * blockDim.x + threadIdx.x;
    int stride = gridDim.x * blockDim.x;
    for (; i < nE; i += stride) {
        int s = src[i], d = dst[i];
        float c = dinv[s] * dinv[d];
        int pos = atomicAdd(&cursor[d], 1);
        erec[pos] = make_int2(s, __float_as_int(c));
    }
}

// ---- Out[r][c] = sum_k X[r][k] * W[k][c], W is 64x64 row-major ----
__global__ void k_gemm64(const float* __restrict__ X, const float* __restrict__ W,
                         float* __restrict__ Out, int nRows) {
    __shared__ float Ws[64][64];
    __shared__ float xs[4][64];
    int tid = threadIdx.x;
    for (int i = tid; i < 64 * 64; i += 256) Ws[i >> 6][i & 63] = W[i];
    __syncthreads();
    int c = tid & 63, rl = tid >> 6;
    for (int r0 = blockIdx.x * 4; r0 < nRows; r0 += gridDim.x * 4) {
        int r = r0 + rl;
        if (r < nRows) xs[rl][c] = X[(size_t)r * 64 + c];
        __syncthreads();
        if (r < nRows) {
            float acc = 0.f;
#pragma unroll
            for (int k = 0; k < 64; ++k) acc = fmaf(xs[rl][k], Ws[k][c], acc);
            Out[(size_t)r * 64 + c] = acc;
        }
        __syncthreads();
    }
}

// ---- fused gather + self-loop + bias (+ReLU): 16 lanes per dst node ----
__global__ void k_gather(const int* __restrict__ rowptr, const int2* __restrict__ erec,
                         const float* __restrict__ H, const float* __restrict__ dinv,
                         const float* __restrict__ b, float* __restrict__ Y,
                         int nN, int relu) {
    int node = blockIdx.x * 16 + (threadIdx.x >> 4);
    int lane = threadIdx.x & 15;
    if (node >= nN) return;
    int e0 = rowptr[node], e1 = rowptr[node + 1];
    const float4* H4 = (const float4*)H;
    float4 acc = make_float4(0.f, 0.f, 0.f, 0.f);
    int e = e0;
    for (; e + 1 < e1; e += 2) {
        int2 r0 = erec[e], r1 = erec[e + 1];
        float c0 = __int_as_float(r0.y), c1 = __int_as_float(r1.y);
        float4 v0 = H4[(size_t)r0.x * 16 + lane];
        float4 v1 = H4[(size_t)r1.x * 16 + lane];
        acc.x = fmaf(c0, v0.x, acc.x); acc.y = fmaf(c0, v0.y, acc.y);
        acc.z = fmaf(c0, v0.z, acc.z); acc.w = fmaf(c0, v0.w, acc.w);
        acc.x = fmaf(c1, v1.x, acc.x); acc.y = fmaf(c1, v1.y, acc.y);
        acc.z = fmaf(c1, v1.z, acc.z); acc.w = fmaf(c1, v1.w, acc.w);
    }
    if (e < e1) {
        int2 r0 = erec[e];
        float c0 = __int_as_float(r0.y);
        float4 v0 = H4[(size_t)r0.x * 16 + lane];
        acc.x = fmaf(c0, v0.x, acc.x); acc.y = fmaf(c0, v0.y, acc.y);
        acc.z = fmaf(c0, v0.z, acc.z); acc.w = fmaf(c0, v0.w, acc.w);
    }
    float di = dinv[node];
    float sc = di * di;
    float4 h = H4[(size_t)node * 16 + lane];
    float4 bb = ((const float4*)b)[lane];
    float x0 = fmaf(h.x, sc, acc.x) + bb.x;
    float x1 = fmaf(h.y, sc, acc.y) + bb.y;
    float x2 = fmaf(h.z, sc, acc.z) + bb.z;
    float x3 = fmaf(h.w, sc, acc.w) + bb.w;
    if (relu) {
        x0 = fmaxf(x0, 0.f); x1 = fmaxf(x1, 0.f);
        x2 = fmaxf(x2, 0.f); x3 = fmaxf(x3, 0.f);
    }
    ((float4*)Y)[(size_t)node * 16 + lane] = make_float4(x0, x1, x2, x3);
}

// ---- pooled sums + counts; batch is sorted, so flush on graph-id change ----
__global__ void k_pool(const float* __restrict__ Y, const int* __restrict__ batch,
                       float* __restrict__ gsum, float* __restrict__ gcnt, int nN) {
    const int CH = 512;
    int n0 = blockIdx.x * CH;
    int f = threadIdx.x & 63, rl = threadIdx.x >> 6;
    int nend = n0 + CH; if (nend > nN) nend = nN;
    int curg = -1;
    float acc = 0.f, cacc = 0.f;
    for (int n = n0 + rl; n < nend; n += 4) {
        int g = batch[n];
        if (g != curg) {
            if (curg >= 0) {
                unsafeAtomicAdd(&gsum[curg * 64 + f], acc);
                if (f == 0) unsafeAtomicAdd(&gcnt[curg], cacc);
            }
            curg = g; acc = 0.f; cacc = 0.f;
        }
        acc += Y[(size_t)n * 64 + f];
        cacc += 1.f;
    }
    if (curg >= 0) {
        unsafeAtomicAdd(&gsum[curg * 64 + f], acc);
        if (f == 0) unsafeAtomicAdd(&gcnt[curg], cacc);
    }
}

// ---- head: mean -> @Wl + bl -> softmax(3) ----
__global__ void k_head(const float* __restrict__ gsum, const float* __restrict__ gcnt,
                       const float* __restrict__ Wl, const float* __restrict__ bl,
                       float* __restrict__ out) {
    int g = threadIdx.x;
    if (g >= NGRAPH) return;
    float inv = 1.0f / fmaxf(gcnt[g], 1.0f);
    float l0 = bl[0], l1 = bl[1], l2 = bl[2];
#pragma unroll
    for (int k = 0; k < 64; ++k) {
        float m = gsum[g * 64 + k] * inv;
        l0 = fmaf(m, Wl[k * 3 + 0], l0);
        l1 = fmaf(m, Wl[k * 3 + 1], l1);
        l2 = fmaf(m, Wl[k * 3 + 2], l2);
    }
    float mx = fmaxf(l0, fmaxf(l1, l2));
    float e0 = expf(l0 - mx), e1 = expf(l1 - mx), e2 = expf(l2 - mx);
    float s = e0 + e1 + e2;
    out[g * 3 + 0] = e0 / s;
    out[g * 3 + 1] = e1 / s;
    out[g * 3 + 2] = e2 / s;
}

extern "C" void kernel_launch(void* const* d_in, const int* in_sizes, int n_in,
                              void* d_out, int out_size, void* d_ws, size_t ws_size,
                              hipStream_t stream) {
    const float* x     = (const float*)d_in[0];
    const int*   ei    = (const int*)d_in[1];
    const int*   batch = (const int*)d_in[2];
    const float* W1    = (const float*)d_in[3];
    const float* b1    = (const float*)d_in[4];
    const float* W2    = (const float*)d_in[5];
    const float* b2    = (const float*)d_in[6];
    const float* Wl    = (const float*)d_in[7];
    const float* bl    = (const float*)d_in[8];
    float* out = (float*)d_out;

    int nN = in_sizes[2];
    int nE = in_sizes[1] / 2;
    const int* srcp = ei;
    const int* dstp = ei + nE;

    char* ws = (char*)d_ws;
    size_t off = 0;
    auto alloc = [&](size_t bytes) -> void* {
        void* p = ws + off;
        off += (bytes + 255) & ~(size_t)255;
        return p;
    };
    float* dinv   = (float*)alloc((size_t)nN * 4);
    int*   cnt    = (int*)alloc((size_t)nN * 4);      // reused as cursor after scan
    int*   rowptr = (int*)alloc(((size_t)nN + 1) * 4);
    int*   bsums  = (int*)alloc(64 * 4);
    int2*  erec   = (int2*)alloc((size_t)nE * 8);
    float* bufA   = (float*)alloc((size_t)nN * 64 * 4);
    float* bufB   = (float*)alloc((size_t)nN * 64 * 4);
    float* gsum   = (float*)alloc(NGRAPH * 64 * 4);
    float* gcnt   = (float*)alloc(NGRAPH * 4);
    int* cursor = cnt;  // alias: cnt dead after k_scanA reads it

    int nB = (nN + SCAN_B - 1) / SCAN_B;

    hipMemsetAsync(cnt, 0, (size_t)nN * 4, stream);
    hipMemsetAsync(gsum, 0, NGRAPH * 64 * 4, stream);
    hipMemsetAsync(gcnt, 0, NGRAPH * 4, stream);

    // degree + norm + CSR
    k_count<<<1024, 256, 0, stream>>>(dstp, cnt, nE);
    k_dinv<<<(nN + 255) / 256, 256, 0, stream>>>(cnt, dinv, nN);
    k_scanA<<<nB, SCAN_T, 0, stream>>>(cnt, rowptr, bsums, nN);
    k_scanB<<<1, 1, 0, stream>>>(bsums, rowptr, nB, nN);
    k_scanC<<<nB, SCAN_T, 0, stream>>>(rowptr, bsums, cursor, nN);
    k_bucket<<<2048, 256, 0, stream>>>(srcp, dstp, dinv, cursor, erec, nE);

    // layer 1: h1 = x@W1 -> bufA ; y1 = gather+combine+relu -> bufB
    k_gemm64<<<1024, 256, 0, stream>>>(x, W1, bufA, nN);
    k_gather<<<(nN + 15) / 16, 256, 0, stream>>>(rowptr, erec, bufA, dinv, b1, bufB, nN, 1);

    // layer 2: h2 = y1@W2 -> bufA ; y2 = gather+combine -> bufB
    k_gemm64<<<1024, 256, 0, stream>>>(bufB, W2, bufA, nN);
    k_gather<<<(nN + 15) / 16, 256, 0, stream>>>(rowptr, erec, bufA, dinv, b2, bufB, nN, 0);

    // pool + head
    k_pool<<<(nN + 511) / 512, 256, 0, stream>>>(bufB, batch, gsum, gcnt, nN);
    k_head<<<1, 64, 0, stream>>>(gsum, gcnt, Wl, bl, out);
}

// Round 3
// 392.619 us; speedup vs baseline: 7.5956x; 1.1574x over previous
//
#include <hip/hip_runtime.h>

// GridGNN: 2x GCNConv(64->64) + ReLU, global_mean_pool, Linear(64->3), softmax.
// N=100000 nodes, E=1600000 edges, G=64 graphs, F=64 feats, fp32 throughout.
// R1: CSR + gather (no fp32 atomics). 2982 -> 454 us.
// R2: 4-B edge records (coef recomputed from dinv), rank-from-count (no cursor
//     atomics), gemm2 folded into pooled head via linearity of S, W2, pooling.

#define FDIM 64
#define NGRAPH 64

#define SCAN_T 256
#define SCAN_E 16
#define SCAN_B (SCAN_T * SCAN_E)  // 4096 elems per scan block

// ---- degree count + within-dst rank: rank[i] = old cnt[dst[i]]++ ----
__global__ void k_count(const int* __restrict__ dst, int* __restrict__ cnt,
                        int* __restrict__ rank, int nE) {
    int i = blockIdx.x * blockDim.x + threadIdx.x;
    int stride = gridDim.x * blockDim.x;
    for (; i < nE; i += stride) rank[i] = atomicAdd(&cnt[dst[i]], 1);
}

// ---- dinv[i] = rsqrt(1 + indeg[i]) ----
__global__ void k_dinv(const int* __restrict__ cnt, float* __restrict__ dinv, int nN) {
    int i = blockIdx.x * blockDim.x + threadIdx.x;
    int stride = gridDim.x * blockDim.x;
    for (; i < nN; i += stride) dinv[i] = rsqrtf(1.0f + (float)cnt[i]);
}

// ---- scan stage A: per-block exclusive scan of cnt -> rowptr, block totals ----
__global__ void k_scanA(const int* __restrict__ cnt, int* __restrict__ rowptr,
                        int* __restrict__ bsums, int nN) {
    __shared__ int sh[SCAN_T];
    int b = blockIdx.x, tid = threadIdx.x;
    int base = b * SCAN_B + tid * SCAN_E;
    int v[SCAN_E];
    int s = 0;
#pragma unroll
    for (int j = 0; j < SCAN_E; ++j) {
        int idx = base + j;
        int c = (idx < nN) ? cnt[idx] : 0;
        v[j] = s;
        s += c;
    }
    sh[tid] = s;
    __syncthreads();
    for (int off = 1; off < SCAN_T; off <<= 1) {
        int t = (tid >= off) ? sh[tid - off] : 0;
        __syncthreads();
        sh[tid] += t;
        __syncthreads();
    }
    int excl = (tid == 0) ? 0 : sh[tid - 1];
    if (tid == SCAN_T - 1) bsums[b] = sh[tid];
#pragma unroll
    for (int j = 0; j < SCAN_E; ++j) {
        int idx = base + j;
        if (idx < nN) rowptr[idx] = excl + v[j];
    }
}

// ---- scan stage B: serial exclusive scan of block sums (nB <= 64) ----
__global__ void k_scanB(int* __restrict__ bsums, int* __restrict__ rowptr, int nB, int nN) {
    int run = 0;
    for (int i = 0; i < nB; ++i) {
        int t = bsums[i];
        bsums[i] = run;
        run += t;
    }
    rowptr[nN] = run;  // == nE
}

// ---- scan stage C: add block offsets ----
__global__ void k_scanC(int* __restrict__ rowptr, const int* __restrict__ bsums, int nN) {
    int b = blockIdx.x, tid = threadIdx.x;
    int add = bsums[b];
    int base = b * SCAN_B;
#pragma unroll
    for (int j = 0; j < SCAN_E; ++j) {
        int idx = base + tid + j * SCAN_T;
        if (idx < nN) rowptr[idx] += add;
    }
}

// ---- bucket edges by dst (no atomics): esrc[rowptr[dst]+rank] = src ----
__global__ void k_bucket(const int* __restrict__ src, const int* __restrict__ dst,
                         const int* __restrict__ rank, const int* __restrict__ rowptr,
                         int* __restrict__ esrc, int nE) {
    int i = blockIdx.x * blockDim.x + threadIdx.x;
    int stride = gridDim.x * blockDim.x;
    for (; i < nE; i += stride) {
        int d = dst[i];
        esrc[rowptr[d] + rank[i]] = src[i];
    }
}

// ---- Out[r][c] = sum_k X[r][k] * W[k][c], W is 64x64 row-major ----
__global__ void k_gemm64(const float* __restrict__ X, const float* __restrict__ W,
                         float* __restrict__ Out, int nRows) {
    __shared__ float Ws[64][64];
    __shared__ float xs[4][64];
    int tid = threadIdx.x;
    for (int i = tid; i < 64 * 64; i += 256) Ws[i >> 6][i & 63] = W[i];
    __syncthreads();
    int c = tid & 63, rl = tid >> 6;
    for (int r0 = blockIdx.x * 4; r0 < nRows; r0 += gridDim.x * 4) {
        int r = r0 + rl;
        if (r < nRows) xs[rl][c] = X[(size_t)r * 64 + c];
        __syncthreads();
        if (r < nRows) {
            float acc = 0.f;
#pragma unroll
            for (int k = 0; k < 64; ++k) acc = fmaf(xs[rl][k], Ws[k][c], acc);
            Out[(size_t)r * 64 + c] = acc;
        }
        __syncthreads();
    }
}

// ---- fused gather + self-loop (+bias)(+ReLU): 16 lanes per dst node ----
// Y[d] = act( dinv[d]*( sum_e dinv[s]*H[s] + dinv[d]*H[d] ) + b )
__global__ void k_gather(const int* __restrict__ rowptr, const int* __restrict__ esrc,
                         const float* __restrict__ H, const float* __restrict__ dinv,
                         const float* __restrict__ b, float* __restrict__ Y,
                         int nN, int relu, int addb) {
    int node = blockIdx.x * 16 + (threadIdx.x >> 4);
    int lane = threadIdx.x & 15;
    if (node >= nN) return;
    int e0 = rowptr[node], e1 = rowptr[node + 1];
    const float4* H4 = (const float4*)H;
    float4 acc = make_float4(0.f, 0.f, 0.f, 0.f);
    int e = e0;
    for (; e + 1 < e1; e += 2) {
        int s0 = esrc[e], s1 = esrc[e + 1];
        float c0 = dinv[s0], c1 = dinv[s1];
        float4 v0 = H4[(size_t)s0 * 16 + lane];
        float4 v1 = H4[(size_t)s1 * 16 + lane];
        acc.x = fmaf(c0, v0.x, acc.x); acc.y = fmaf(c0, v0.y, acc.y);
        acc.z = fmaf(c0, v0.z, acc.z); acc.w = fmaf(c0, v0.w, acc.w);
        acc.x = fmaf(c1, v1.x, acc.x); acc.y = fmaf(c1, v1.y, acc.y);
        acc.z = fmaf(c1, v1.z, acc.z); acc.w = fmaf(c1, v1.w, acc.w);
    }
    if (e < e1) {
        int s0 = esrc[e];
        float c0 = dinv[s0];
        float4 v0 = H4[(size_t)s0 * 16 + lane];
        acc.x = fmaf(c0, v0.x, acc.x); acc.y = fmaf(c0, v0.y, acc.y);
        acc.z = fmaf(c0, v0.z, acc.z); acc.w = fmaf(c0, v0.w, acc.w);
    }
    float di = dinv[node];
    float4 h = H4[(size_t)node * 16 + lane];
    float x0 = di * fmaf(di, h.x, acc.x);
    float x1 = di * fmaf(di, h.y, acc.y);
    float x2 = di * fmaf(di, h.z, acc.z);
    float x3 = di * fmaf(di, h.w, acc.w);
    if (addb) {
        float4 bb = ((const float4*)b)[lane];
        x0 += bb.x; x1 += bb.y; x2 += bb.z; x3 += bb.w;
    }
    if (relu) {
        x0 = fmaxf(x0, 0.f); x1 = fmaxf(x1, 0.f);
        x2 = fmaxf(x2, 0.f); x3 = fmaxf(x3, 0.f);
    }
    ((float4*)Y)[(size_t)node * 16 + lane] = make_float4(x0, x1, x2, x3);
}

// ---- pooled sums + counts; batch is sorted, so flush on graph-id change ----
__global__ void k_pool(const float* __restrict__ Y, const int* __restrict__ batch,
                       float* __restrict__ gsum, float* __restrict__ gcnt, int nN) {
    const int CH = 512;
    int n0 = blockIdx.x * CH;
    int f = threadIdx.x & 63, rl = threadIdx.x >> 6;
    int nend = n0 + CH; if (nend > nN) nend = nN;
    int curg = -1;
    float acc = 0.f, cacc = 0.f;
    for (int n = n0 + rl; n < nend; n += 4) {
        int g = batch[n];
        if (g != curg) {
            if (curg >= 0) {
                unsafeAtomicAdd(&gsum[curg * 64 + f], acc);
                if (f == 0) unsafeAtomicAdd(&gcnt[curg], cacc);
            }
            curg = g; acc = 0.f; cacc = 0.f;
        }
        acc += Y[(size_t)n * 64 + f];
        cacc += 1.f;
    }
    if (curg >= 0) {
        unsafeAtomicAdd(&gsum[curg * 64 + f], acc);
        if (f == 0) unsafeAtomicAdd(&gcnt[curg], cacc);
    }
}

// ---- head: mean -> @W2 + b2 -> @Wl + bl -> softmax(3), all on pooled [64,64] ----
__global__ void k_head(const float* __restrict__ gsum, const float* __restrict__ gcnt,
                       const float* __restrict__ W2, const float* __restrict__ b2,
                       const float* __restrict__ Wl, const float* __restrict__ bl,
                       float* __restrict__ out) {
    __shared__ float m[64][65];   // +1 pad: avoid stride-64 bank conflicts
    __shared__ float t[64][65];
    int tid = threadIdx.x;  // 256
    for (int i = tid; i < 64 * 64; i += 256) {
        int g = i >> 6, k = i & 63;
        m[g][k] = gsum[i] / fmaxf(gcnt[g], 1.f);
    }
    __syncthreads();
    int g = tid & 63, c0 = (tid >> 6) << 4;
    for (int c = c0; c < c0 + 16; ++c) {
        float acc = b2[c];
#pragma unroll
        for (int k = 0; k < 64; ++k) acc = fmaf(m[g][k], W2[k * 64 + c], acc);
        t[g][c] = acc;
    }
    __syncthreads();
    if (tid < 64) {
        float l0 = bl[0], l1 = bl[1], l2 = bl[2];
#pragma unroll
        for (int cc = 0; cc < 64; ++cc) {
            float v = t[tid][cc];
            l0 = fmaf(v, Wl[cc * 3 + 0], l0);
            l1 = fmaf(v, Wl[cc * 3 + 1], l1);
            l2 = fmaf(v, Wl[cc * 3 + 2], l2);
        }
        float mx = fmaxf(l0, fmaxf(l1, l2));
        float e0 = expf(l0 - mx), e1 = expf(l1 - mx), e2 = expf(l2 - mx);
        float s = e0 + e1 + e2;
        out[tid * 3 + 0] = e0 / s;
        out[tid * 3 + 1] = e1 / s;
        out[tid * 3 + 2] = e2 / s;
    }
}

extern "C" void kernel_launch(void* const* d_in, const int* in_sizes, int n_in,
                              void* d_out, int out_size, void* d_ws, size_t ws_size,
                              hipStream_t stream) {
    const float* x     = (const float*)d_in[0];
    const int*   ei    = (const int*)d_in[1];
    const int*   batch = (const int*)d_in[2];
    const float* W1    = (const float*)d_in[3];
    const float* b1    = (const float*)d_in[4];
    const float* W2    = (const float*)d_in[5];
    const float* b2    = (const float*)d_in[6];
    const float* Wl    = (const float*)d_in[7];
    const float* bl    = (const float*)d_in[8];
    float* out = (float*)d_out;

    int nN = in_sizes[2];
    int nE = in_sizes[1] / 2;
    const int* srcp = ei;
    const int* dstp = ei + nE;

    char* ws = (char*)d_ws;
    size_t off = 0;
    auto alloc = [&](size_t bytes) -> void* {
        void* p = ws + off;
        off += (bytes + 255) & ~(size_t)255;
        return p;
    };
    float* dinv   = (float*)alloc((size_t)nN * 4);
    int*   cnt    = (int*)alloc((size_t)nN * 4);
    int*   rank   = (int*)alloc((size_t)nE * 4);
    int*   rowptr = (int*)alloc(((size_t)nN + 1) * 4);
    int*   bsums  = (int*)alloc(64 * 4);
    int*   esrc   = (int*)alloc((size_t)nE * 4);
    float* bufA   = (float*)alloc((size_t)nN * 64 * 4);
    float* bufB   = (float*)alloc((size_t)nN * 64 * 4);
    float* gsum   = (float*)alloc(NGRAPH * 64 * 4);
    float* gcnt   = (float*)alloc(NGRAPH * 4);

    int nB = (nN + SCAN_B - 1) / SCAN_B;

    hipMemsetAsync(cnt, 0, (size_t)nN * 4, stream);
    hipMemsetAsync(gsum, 0, NGRAPH * 64 * 4, stream);
    hipMemsetAsync(gcnt, 0, NGRAPH * 4, stream);

    // degree(+rank) + norm + CSR
    k_count<<<1024, 256, 0, stream>>>(dstp, cnt, rank, nE);
    k_dinv<<<(nN + 255) / 256, 256, 0, stream>>>(cnt, dinv, nN);
    k_scanA<<<nB, SCAN_T, 0, stream>>>(cnt, rowptr, bsums, nN);
    k_scanB<<<1, 1, 0, stream>>>(bsums, rowptr, nB, nN);
    k_scanC<<<nB, SCAN_T, 0, stream>>>(rowptr, bsums, nN);
    k_bucket<<<2048, 256, 0, stream>>>(srcp, dstp, rank, rowptr, esrc, nE);

    // layer 1: h1 = x@W1 -> bufA ; y1 = gather+bias+relu -> bufB
    k_gemm64<<<1024, 256, 0, stream>>>(x, W1, bufA, nN);
    k_gather<<<(nN + 15) / 16, 256, 0, stream>>>(rowptr, esrc, bufA, dinv, b1, bufB, nN, 1, 1);

    // layer 2 (reordered): z = S*y1 -> bufA ; W2/b2 applied post-pool in head
    k_gather<<<(nN + 15) / 16, 256, 0, stream>>>(rowptr, esrc, bufB, dinv, nullptr, bufA, nN, 0, 0);

    // pool z + head (mean -> @W2+b2 -> @Wl+bl -> softmax)
    k_pool<<<(nN + 511) / 512, 256, 0, stream>>>(bufA, batch, gsum, gcnt, nN);
    k_head<<<1, 256, 0, stream>>>(gsum, gcnt, W2, b2, Wl, bl, out);
}

// Round 4
// 331.899 us; speedup vs baseline: 8.9851x; 1.1829x over previous
//
#include <hip/hip_runtime.h>

// GridGNN: 2x GCNConv(64->64) + ReLU, global_mean_pool, Linear(64->3), softmax.
// N=100000 nodes, E=1600000 edges, G=64 graphs, F=64 feats, fp32 throughout.
// R1: CSR + gather (no fp32 atomics). 2982 -> 454 us.
// R2: 4-B edge records, rank-from-count, gemm2 folded past pooling. -> 393 us.
// R3: head folded to m@(W2@Wl)+(b2@Wl+bl) (was 73 us single-block latency);
//     gemm1 fused into count dispatch (rides under atomic latency);
//     dinv fused into scanA; gather unrolled 4-wide.

#define FDIM 64
#define NGRAPH 64

#define SCAN_T 256
#define SCAN_E 16
#define SCAN_B (SCAN_T * SCAN_E)  // 4096 elems per scan block

#define GEMM_BLOCKS 1024
#define CNT_BLOCKS 1024

// ---- fused: blocks [0,GEMM_BLOCKS): Out = X@W1 ; rest: degree count + rank ----
__global__ void k_gemm_count(const float* __restrict__ X, const float* __restrict__ W,
                             float* __restrict__ Out, int nRows,
                             const int* __restrict__ dst, int* __restrict__ cnt,
                             int* __restrict__ rank, int nE) {
    int tid = threadIdx.x;
    if (blockIdx.x < GEMM_BLOCKS) {
        __shared__ float Ws[64][64];
        __shared__ float xs[4][64];
        for (int i = tid; i < 64 * 64; i += 256) Ws[i >> 6][i & 63] = W[i];
        __syncthreads();
        int c = tid & 63, rl = tid >> 6;
        for (int r0 = blockIdx.x * 4; r0 < nRows; r0 += GEMM_BLOCKS * 4) {
            int r = r0 + rl;
            if (r < nRows) xs[rl][c] = X[(size_t)r * 64 + c];
            __syncthreads();
            if (r < nRows) {
                float acc = 0.f;
#pragma unroll
                for (int k = 0; k < 64; ++k) acc = fmaf(xs[rl][k], Ws[k][c], acc);
                Out[(size_t)r * 64 + c] = acc;
            }
            __syncthreads();
        }
    } else {
        int i = (blockIdx.x - GEMM_BLOCKS) * 256 + tid;
        int stride = CNT_BLOCKS * 256;
        for (; i < nE; i += stride) rank[i] = atomicAdd(&cnt[dst[i]], 1);
    }
}

// ---- scan stage A + dinv: per-block exclusive scan of cnt -> rowptr ----
__global__ void k_scanA(const int* __restrict__ cnt, int* __restrict__ rowptr,
                        int* __restrict__ bsums, float* __restrict__ dinv, int nN) {
    __shared__ int sh[SCAN_T];
    int b = blockIdx.x, tid = threadIdx.x;
    int base = b * SCAN_B + tid * SCAN_E;
    int v[SCAN_E];
    int s = 0;
#pragma unroll
    for (int j = 0; j < SCAN_E; ++j) {
        int idx = base + j;
        int c = (idx < nN) ? cnt[idx] : 0;
        if (idx < nN) dinv[idx] = rsqrtf(1.0f + (float)c);
        v[j] = s;
        s += c;
    }
    sh[tid] = s;
    __syncthreads();
    for (int off = 1; off < SCAN_T; off <<= 1) {
        int t = (tid >= off) ? sh[tid - off] : 0;
        __syncthreads();
        sh[tid] += t;
        __syncthreads();
    }
    int excl = (tid == 0) ? 0 : sh[tid - 1];
    if (tid == SCAN_T - 1) bsums[b] = sh[tid];
#pragma unroll
    for (int j = 0; j < SCAN_E; ++j) {
        int idx = base + j;
        if (idx < nN) rowptr[idx] = excl + v[j];
    }
}

// ---- scan stage B (1 block): serial scan of block sums on t0; other lanes
//      fold head weights: Wc = W2@Wl [64x3], bc = b2@Wl + bl [3] ----
__global__ void k_scanB_fold(int* __restrict__ bsums, int* __restrict__ rowptr,
                             int nB, int nN,
                             const float* __restrict__ W2, const float* __restrict__ b2,
                             const float* __restrict__ Wl, const float* __restrict__ bl,
                             float* __restrict__ Wc, float* __restrict__ bc) {
    int tid = threadIdx.x;
    if (tid == 0) {
        int run = 0;
        for (int i = 0; i < nB; ++i) {
            int t = bsums[i];
            bsums[i] = run;
            run += t;
        }
        rowptr[nN] = run;  // == nE
    } else if (tid >= 64 && tid < 64 + 192) {
        int i = tid - 64;           // 0..191
        int k = i / 3, j = i % 3;
        float acc = 0.f;
#pragma unroll
        for (int c = 0; c < 64; ++c) acc = fmaf(W2[k * 64 + c], Wl[c * 3 + j], acc);
        Wc[k * 3 + j] = acc;
    } else if (tid >= 1 && tid <= 3) {
        int j = tid - 1;
        float acc = bl[j];
#pragma unroll
        for (int c = 0; c < 64; ++c) acc = fmaf(b2[c], Wl[c * 3 + j], acc);
        bc[j] = acc;
    }
}

// ---- scan stage C: add block offsets ----
__global__ void k_scanC(int* __restrict__ rowptr, const int* __restrict__ bsums, int nN) {
    int b = blockIdx.x, tid = threadIdx.x;
    int add = bsums[b];
    int base = b * SCAN_B;
#pragma unroll
    for (int j = 0; j < SCAN_E; ++j) {
        int idx = base + tid + j * SCAN_T;
        if (idx < nN) rowptr[idx] += add;
    }
}

// ---- bucket edges by dst (no atomics): esrc[rowptr[dst]+rank] = src ----
__global__ void k_bucket(const int* __restrict__ src, const int* __restrict__ dst,
                         const int* __restrict__ rank, const int* __restrict__ rowptr,
                         int* __restrict__ esrc, int nE) {
    int i = blockIdx.x * blockDim.x + threadIdx.x;
    int stride = gridDim.x * blockDim.x;
    for (; i < nE; i += stride) {
        int d = dst[i];
        esrc[rowptr[d] + rank[i]] = src[i];
    }
}

// ---- plain 64x64 GEMM (used for nothing now; kept for layer-2 path if needed) ----

// ---- fused gather + self-loop (+bias)(+ReLU): 16 lanes per dst node ----
// Y[d] = act( dinv[d]*( sum_e dinv[s]*H[s] + dinv[d]*H[d] ) + b )
__global__ void k_gather(const int* __restrict__ rowptr, const int* __restrict__ esrc,
                         const float* __restrict__ H, const float* __restrict__ dinv,
                         const float* __restrict__ b, float* __restrict__ Y,
                         int nN, int relu, int addb) {
    int node = blockIdx.x * 16 + (threadIdx.x >> 4);
    int lane = threadIdx.x & 15;
    if (node >= nN) return;
    int e0 = rowptr[node], e1 = rowptr[node + 1];
    const float4* H4 = (const float4*)H;
    float4 acc = make_float4(0.f, 0.f, 0.f, 0.f);
    int e = e0;
    for (; e + 3 < e1; e += 4) {
        int s0 = esrc[e], s1 = esrc[e + 1], s2 = esrc[e + 2], s3 = esrc[e + 3];
        float c0 = dinv[s0], c1 = dinv[s1], c2 = dinv[s2], c3 = dinv[s3];
        float4 v0 = H4[(size_t)s0 * 16 + lane];
        float4 v1 = H4[(size_t)s1 * 16 + lane];
        float4 v2 = H4[(size_t)s2 * 16 + lane];
        float4 v3 = H4[(size_t)s3 * 16 + lane];
        acc.x = fmaf(c0, v0.x, acc.x); acc.y = fmaf(c0, v0.y, acc.y);
        acc.z = fmaf(c0, v0.z, acc.z); acc.w = fmaf(c0, v0.w, acc.w);
        acc.x = fmaf(c1, v1.x, acc.x); acc.y = fmaf(c1, v1.y, acc.y);
        acc.z = fmaf(c1, v1.z, acc.z); acc.w = fmaf(c1, v1.w, acc.w);
        acc.x = fmaf(c2, v2.x, acc.x); acc.y = fmaf(c2, v2.y, acc.y);
        acc.z = fmaf(c2, v2.z, acc.z); acc.w = fmaf(c2, v2.w, acc.w);
        acc.x = fmaf(c3, v3.x, acc.x); acc.y = fmaf(c3, v3.y, acc.y);
        acc.z = fmaf(c3, v3.z, acc.z); acc.w = fmaf(c3, v3.w, acc.w);
    }
    for (; e < e1; ++e) {
        int s0 = esrc[e];
        float c0 = dinv[s0];
        float4 v0 = H4[(size_t)s0 * 16 + lane];
        acc.x = fmaf(c0, v0.x, acc.x); acc.y = fmaf(c0, v0.y, acc.y);
        acc.z = fmaf(c0, v0.z, acc.z); acc.w = fmaf(c0, v0.w, acc.w);
    }
    float di = dinv[node];
    float4 h = H4[(size_t)node * 16 + lane];
    float x0 = di * fmaf(di, h.x, acc.x);
    float x1 = di * fmaf(di, h.y, acc.y);
    float x2 = di * fmaf(di, h.z, acc.z);
    float x3 = di * fmaf(di, h.w, acc.w);
    if (addb) {
        float4 bb = ((const float4*)b)[lane];
        x0 += bb.x; x1 += bb.y; x2 += bb.z; x3 += bb.w;
    }
    if (relu) {
        x0 = fmaxf(x0, 0.f); x1 = fmaxf(x1, 0.f);
        x2 = fmaxf(x2, 0.f); x3 = fmaxf(x3, 0.f);
    }
    ((float4*)Y)[(size_t)node * 16 + lane] = make_float4(x0, x1, x2, x3);
}

// ---- pooled sums + counts; batch is sorted, so flush on graph-id change ----
__global__ void k_pool(const float* __restrict__ Y, const int* __restrict__ batch,
                       float* __restrict__ gsum, float* __restrict__ gcnt, int nN) {
    const int CH = 512;
    int n0 = blockIdx.x * CH;
    int f = threadIdx.x & 63, rl = threadIdx.x >> 6;
    int nend = n0 + CH; if (nend > nN) nend = nN;
    int curg = -1;
    float acc = 0.f, cacc = 0.f;
    for (int n = n0 + rl; n < nend; n += 4) {
        int g = batch[n];
        if (g != curg) {
            if (curg >= 0) {
                unsafeAtomicAdd(&gsum[curg * 64 + f], acc);
                if (f == 0) unsafeAtomicAdd(&gcnt[curg], cacc);
            }
            curg = g; acc = 0.f; cacc = 0.f;
        }
        acc += Y[(size_t)n * 64 + f];
        cacc += 1.f;
    }
    if (curg >= 0) {
        unsafeAtomicAdd(&gsum[curg * 64 + f], acc);
        if (f == 0) unsafeAtomicAdd(&gcnt[curg], cacc);
    }
}

// ---- head: out[g] = softmax( mean_g @ Wc + bc ), Wc [64x3] ----
__global__ void k_head(const float* __restrict__ gsum, const float* __restrict__ gcnt,
                       const float* __restrict__ Wc, const float* __restrict__ bc,
                       float* __restrict__ out) {
    int g = threadIdx.x;
    if (g >= NGRAPH) return;
    float inv = 1.0f / fmaxf(gcnt[g], 1.0f);
    float l0 = bc[0], l1 = bc[1], l2 = bc[2];
#pragma unroll
    for (int k = 0; k < 64; ++k) {
        float m = gsum[g * 64 + k] * inv;
        l0 = fmaf(m, Wc[k * 3 + 0], l0);
        l1 = fmaf(m, Wc[k * 3 + 1], l1);
        l2 = fmaf(m, Wc[k * 3 + 2], l2);
    }
    float mx = fmaxf(l0, fmaxf(l1, l2));
    float e0 = expf(l0 - mx), e1 = expf(l1 - mx), e2 = expf(l2 - mx);
    float s = e0 + e1 + e2;
    out[g * 3 + 0] = e0 / s;
    out[g * 3 + 1] = e1 / s;
    out[g * 3 + 2] = e2 / s;
}

extern "C" void kernel_launch(void* const* d_in, const int* in_sizes, int n_in,
                              void* d_out, int out_size, void* d_ws, size_t ws_size,
                              hipStream_t stream) {
    const float* x     = (const float*)d_in[0];
    const int*   ei    = (const int*)d_in[1];
    const int*   batch = (const int*)d_in[2];
    const float* W1    = (const float*)d_in[3];
    const float* b1    = (const float*)d_in[4];
    const float* W2    = (const float*)d_in[5];
    const float* b2    = (const float*)d_in[6];
    const float* Wl    = (const float*)d_in[7];
    const float* bl    = (const float*)d_in[8];
    float* out = (float*)d_out;

    int nN = in_sizes[2];
    int nE = in_sizes[1] / 2;
    const int* srcp = ei;
    const int* dstp = ei + nE;

    char* ws = (char*)d_ws;
    size_t off = 0;
    auto alloc = [&](size_t bytes) -> void* {
        void* p = ws + off;
        off += (bytes + 255) & ~(size_t)255;
        return p;
    };
    float* dinv   = (float*)alloc((size_t)nN * 4);
    int*   cnt    = (int*)alloc((size_t)nN * 4);
    int*   rank   = (int*)alloc((size_t)nE * 4);
    int*   rowptr = (int*)alloc(((size_t)nN + 1) * 4);
    int*   bsums  = (int*)alloc(64 * 4);
    int*   esrc   = (int*)alloc((size_t)nE * 4);
    float* bufA   = (float*)alloc((size_t)nN * 64 * 4);
    float* bufB   = (float*)alloc((size_t)nN * 64 * 4);
    float* gsum   = (float*)alloc(NGRAPH * 64 * 4);
    float* gcnt   = (float*)alloc(NGRAPH * 4);
    float* Wc     = (float*)alloc(64 * 3 * 4);
    float* bc     = (float*)alloc(3 * 4);

    int nB = (nN + SCAN_B - 1) / SCAN_B;

    hipMemsetAsync(cnt, 0, (size_t)nN * 4, stream);
    hipMemsetAsync(gsum, 0, NGRAPH * 64 * 4, stream);
    hipMemsetAsync(gcnt, 0, NGRAPH * 4, stream);

    // fused: h1 = x@W1 -> bufA  ||  degree count + rank
    k_gemm_count<<<GEMM_BLOCKS + CNT_BLOCKS, 256, 0, stream>>>(
        x, W1, bufA, nN, dstp, cnt, rank, nE);

    // CSR finalize (+dinv, +head-weight folding on idle lanes)
    k_scanA<<<nB, SCAN_T, 0, stream>>>(cnt, rowptr, bsums, dinv, nN);
    k_scanB_fold<<<1, 256, 0, stream>>>(bsums, rowptr, nB, nN, W2, b2, Wl, bl, Wc, bc);
    k_scanC<<<nB, SCAN_T, 0, stream>>>(rowptr, bsums, nN);
    k_bucket<<<2048, 256, 0, stream>>>(srcp, dstp, rank, rowptr, esrc, nE);

    // layer 1: y1 = gather(h1)+b1+relu -> bufB
    k_gather<<<(nN + 15) / 16, 256, 0, stream>>>(rowptr, esrc, bufA, dinv, b1, bufB, nN, 1, 1);
    // layer 2 (reordered): z = S*y1 -> bufA ; W2/b2 folded into head
    k_gather<<<(nN + 15) / 16, 256, 0, stream>>>(rowptr, esrc, bufB, dinv, nullptr, bufA, nN, 0, 0);

    // pool z + folded head
    k_pool<<<(nN + 511) / 512, 256, 0, stream>>>(bufA, batch, gsum, gcnt, nN);
    k_head<<<1, 64, 0, stream>>>(gsum, gcnt, Wc, bc, out);
}

// Round 5
// 235.503 us; speedup vs baseline: 12.6629x; 1.4093x over previous
//
#include <hip/hip_runtime.h>

// GridGNN: 2x GCNConv(64->64) + ReLU, global_mean_pool, Linear(64->3), softmax.
// N=100000 nodes, E=1600000 edges, G=64 graphs, F=64 feats.
// R1: CSR + gather (no fp32 atomics). 2982 -> 454 us.
// R2: 4-B edge records, gemm2 folded past pooling. -> 393 us.
// R3: head folded; gemm+count fused (fusion HURT: atomics lost TLP). -> 332 us.
// R4: atomic-free CSR via LDS radix partition (391 buckets of 256 dst);
//     bf16 feature rows for gathers (fp32 accum) -> halves row-gather bytes;
//     gemm unfused again.

typedef unsigned int u32;

#define NGRAPH 64
#define SCAN_T 256
#define SCAN_E 16
#define SCAN_B 4096
#define NB1 256  // blocks in hist/partition passes

// ---- bf16 helpers (RN pack, exact unpack) ----
__device__ __forceinline__ float bflo(u32 v) { return __uint_as_float(v << 16); }
__device__ __forceinline__ float bfhi(u32 v) { return __uint_as_float(v & 0xffff0000u); }
__device__ __forceinline__ u32 packbf(float a, float b) {
    u32 ua = __float_as_uint(a); ua += 0x7fff + ((ua >> 16) & 1);
    u32 ub = __float_as_uint(b); ub += 0x7fff + ((ub >> 16) & 1);
    return (ua >> 16) | ((ub >> 16) << 16);
}

// ---- gemm: Out(bf16 packed) = X @ W ; one wave per row (64 cols) ----
__global__ void k_gemm_bf(const float* __restrict__ X, const float* __restrict__ W,
                          u32* __restrict__ Out, int nRows) {
    __shared__ float Ws[64][64];
    __shared__ float xs[4][64];
    int tid = threadIdx.x;
    for (int i = tid; i < 64 * 64; i += 256) Ws[i >> 6][i & 63] = W[i];
    __syncthreads();
    int c = tid & 63, rl = tid >> 6;
    for (int r0 = blockIdx.x * 4; r0 < nRows; r0 += gridDim.x * 4) {
        int r = r0 + rl;
        if (r < nRows) xs[rl][c] = X[(size_t)r * 64 + c];
        __syncthreads();
        if (r < nRows) {
            float acc = 0.f;
#pragma unroll
            for (int k = 0; k < 64; ++k) acc = fmaf(xs[rl][k], Ws[k][c], acc);
            float other = __shfl_xor(acc, 1, 64);
            if (!(c & 1)) Out[(size_t)r * 32 + (c >> 1)] = packbf(acc, other);
        }
        __syncthreads();
    }
}

// ---- pass 1a: per-block LDS histogram over dst>>8 -> histT[bucket*NB1+block] ----
__global__ void k_hist(const int* __restrict__ dst, int* __restrict__ histT,
                       int nE, int NBUCK) {
    __shared__ int h[512];
    int tid = threadIdx.x;
    for (int k = tid; k < NBUCK; k += 256) h[k] = 0;
    __syncthreads();
    int i = blockIdx.x * 256 + tid, stride = NB1 * 256;
    for (; i < nE; i += stride) atomicAdd(&h[dst[i] >> 8], 1);
    __syncthreads();
    for (int k = tid; k < NBUCK; k += 256) histT[k * NB1 + blockIdx.x] = h[k];
}

// ---- scan stage A: per-block exclusive scan of arr[L] -> out, block totals ----
__global__ void k_scanA(const int* __restrict__ arr, int* __restrict__ outp,
                        int* __restrict__ bsums, int L) {
    __shared__ int sh[SCAN_T];
    int b = blockIdx.x, tid = threadIdx.x;
    int base = b * SCAN_B + tid * SCAN_E;
    int v[SCAN_E];
    int s = 0;
#pragma unroll
    for (int j = 0; j < SCAN_E; ++j) {
        int idx = base + j;
        int c = (idx < L) ? arr[idx] : 0;
        v[j] = s;
        s += c;
    }
    sh[tid] = s;
    __syncthreads();
    for (int off = 1; off < SCAN_T; off <<= 1) {
        int t = (tid >= off) ? sh[tid - off] : 0;
        __syncthreads();
        sh[tid] += t;
        __syncthreads();
    }
    int excl = (tid == 0) ? 0 : sh[tid - 1];
    if (tid == SCAN_T - 1) bsums[b] = sh[tid];
#pragma unroll
    for (int j = 0; j < SCAN_E; ++j) {
        int idx = base + j;
        if (idx < L) outp[idx] = excl + v[j];
    }
}

// ---- scan stage B (1 block): serial scan of block sums on t0; idle lanes
//      fold head weights: Wc = W2@Wl [64x3], bc = b2@Wl + bl [3] ----
__global__ void k_scanB_fold(int* __restrict__ bsums, int nB,
                             const float* __restrict__ W2, const float* __restrict__ b2,
                             const float* __restrict__ Wl, const float* __restrict__ bl,
                             float* __restrict__ Wc, float* __restrict__ bc) {
    int tid = threadIdx.x;
    if (tid == 0) {
        int run = 0;
        for (int i = 0; i < nB; ++i) {
            int t = bsums[i];
            bsums[i] = run;
            run += t;
        }
    } else if (tid >= 64 && tid < 64 + 192) {
        int i = tid - 64;
        int k = i / 3, j = i % 3;
        float acc = 0.f;
#pragma unroll
        for (int c = 0; c < 64; ++c) acc = fmaf(W2[k * 64 + c], Wl[c * 3 + j], acc);
        Wc[k * 3 + j] = acc;
    } else if (tid >= 1 && tid <= 3) {
        int j = tid - 1;
        float acc = bl[j];
#pragma unroll
        for (int c = 0; c < 64; ++c) acc = fmaf(b2[c], Wl[c * 3 + j], acc);
        bc[j] = acc;
    }
}

// ---- scan stage C: add block offsets ----
__global__ void k_scanC(int* __restrict__ outp, const int* __restrict__ bsums, int L) {
    int b = blockIdx.x, tid = threadIdx.x;
    int add = bsums[b];
    int base = b * SCAN_B;
#pragma unroll
    for (int j = 0; j < SCAN_E; ++j) {
        int idx = base + tid + j * SCAN_T;
        if (idx < L) outp[idx] += add;
    }
}

// ---- pass 1c: partition edges into buckets via LDS cursors (no global atomics) ----
// staged[pos] = src | (dst&255)<<20   (src < 2^20)
__global__ void k_partition(const int* __restrict__ src, const int* __restrict__ dst,
                            const int* __restrict__ scanned, u32* __restrict__ staged,
                            int nE, int NBUCK) {
    __shared__ int cur[512];
    int tid = threadIdx.x;
    for (int k = tid; k < NBUCK; k += 256) cur[k] = scanned[k * NB1 + blockIdx.x];
    __syncthreads();
    int i = blockIdx.x * 256 + tid, stride = NB1 * 256;
    for (; i < nE; i += stride) {
        int d = dst[i];
        int k = d >> 8;
        int pos = atomicAdd(&cur[k], 1);
        staged[pos] = (u32)src[i] | ((u32)(d & 255) << 20);
    }
}

// ---- pass 2: per-bucket (256 dst) LDS count+scan+place -> esrc, rowptr, dinv ----
__global__ void k_pass2(const u32* __restrict__ staged, const int* __restrict__ scanned,
                        float* __restrict__ dinv, int* __restrict__ rowptr,
                        int* __restrict__ esrc, int nN, int nE, int NBUCK) {
    __shared__ int cnt[256], cur[256], sh[256];
    int bk = blockIdx.x, tid = threadIdx.x;
    int base = scanned[bk * NB1];
    int end = (bk + 1 < NBUCK) ? scanned[(bk + 1) * NB1] : nE;
    cnt[tid] = 0;
    __syncthreads();
    for (int e = base + tid; e < end; e += 256) atomicAdd(&cnt[staged[e] >> 20], 1);
    __syncthreads();
    int v = cnt[tid];
    sh[tid] = v;
    __syncthreads();
    for (int off = 1; off < 256; off <<= 1) {
        int t = (tid >= off) ? sh[tid - off] : 0;
        __syncthreads();
        sh[tid] += t;
        __syncthreads();
    }
    int excl = sh[tid] - v;
    int node = bk * 256 + tid;
    if (node < nN) {
        rowptr[node] = base + excl;
        dinv[node] = rsqrtf(1.0f + (float)v);
    }
    cur[tid] = excl;
    __syncthreads();
    for (int e = base + tid; e < end; e += 256) {
        u32 r = staged[e];
        int j = r >> 20;
        int pos = atomicAdd(&cur[j], 1);
        esrc[base + pos] = (int)(r & 0xFFFFFu);
    }
    if (bk == 0 && tid == 0) rowptr[nN] = nE;
}

// ---- fused gather (bf16 rows, fp32 accum) + self-loop (+bias)(+ReLU) ----
__global__ void k_gather_bf(const int* __restrict__ rowptr, const int* __restrict__ esrc,
                            const uint2* __restrict__ H, const float* __restrict__ dinv,
                            const float* __restrict__ bias, uint2* __restrict__ Obf,
                            float4* __restrict__ Of, int nN, int relu, int addb, int outbf) {
    int node = blockIdx.x * 16 + (threadIdx.x >> 4);
    int lane = threadIdx.x & 15;
    if (node >= nN) return;
    int e0 = rowptr[node], e1 = rowptr[node + 1];
    float4 acc = make_float4(0.f, 0.f, 0.f, 0.f);
#define GSTEP(s, cc) { uint2 v = H[(size_t)(s) * 16 + lane]; \
        acc.x = fmaf(cc, bflo(v.x), acc.x); acc.y = fmaf(cc, bfhi(v.x), acc.y); \
        acc.z = fmaf(cc, bflo(v.y), acc.z); acc.w = fmaf(cc, bfhi(v.y), acc.w); }
    int e = e0;
    for (; e + 3 < e1; e += 4) {
        int s0 = esrc[e], s1 = esrc[e + 1], s2 = esrc[e + 2], s3 = esrc[e + 3];
        float c0 = dinv[s0], c1 = dinv[s1], c2 = dinv[s2], c3 = dinv[s3];
        GSTEP(s0, c0) GSTEP(s1, c1) GSTEP(s2, c2) GSTEP(s3, c3)
    }
    for (; e < e1; ++e) {
        int s = esrc[e];
        float c = dinv[s];
        GSTEP(s, c)
    }
#undef GSTEP
    float di = dinv[node];
    uint2 hv = H[(size_t)node * 16 + lane];
    float x0 = di * fmaf(di, bflo(hv.x), acc.x);
    float x1 = di * fmaf(di, bfhi(hv.x), acc.y);
    float x2 = di * fmaf(di, bflo(hv.y), acc.z);
    float x3 = di * fmaf(di, bfhi(hv.y), acc.w);
    if (addb) {
        float4 bb = ((const float4*)bias)[lane];
        x0 += bb.x; x1 += bb.y; x2 += bb.z; x3 += bb.w;
    }
    if (relu) {
        x0 = fmaxf(x0, 0.f); x1 = fmaxf(x1, 0.f);
        x2 = fmaxf(x2, 0.f); x3 = fmaxf(x3, 0.f);
    }
    if (outbf) Obf[(size_t)node * 16 + lane] = make_uint2(packbf(x0, x1), packbf(x2, x3));
    else       Of[(size_t)node * 16 + lane] = make_float4(x0, x1, x2, x3);
}

// ---- pooled sums + counts; batch is sorted, so flush on graph-id change ----
__global__ void k_pool(const float* __restrict__ Y, const int* __restrict__ batch,
                       float* __restrict__ gsum, float* __restrict__ gcnt, int nN) {
    const int CH = 512;
    int n0 = blockIdx.x * CH;
    int f = threadIdx.x & 63, rl = threadIdx.x >> 6;
    int nend = n0 + CH; if (nend > nN) nend = nN;
    int curg = -1;
    float acc = 0.f, cacc = 0.f;
    for (int n = n0 + rl; n < nend; n += 4) {
        int g = batch[n];
        if (g != curg) {
            if (curg >= 0) {
                unsafeAtomicAdd(&gsum[curg * 64 + f], acc);
                if (f == 0) unsafeAtomicAdd(&gcnt[curg], cacc);
            }
            curg = g; acc = 0.f; cacc = 0.f;
        }
        acc += Y[(size_t)n * 64 + f];
        cacc += 1.f;
    }
    if (curg >= 0) {
        unsafeAtomicAdd(&gsum[curg * 64 + f], acc);
        if (f == 0) unsafeAtomicAdd(&gcnt[curg], cacc);
    }
}

// ---- head: out[g] = softmax( mean_g @ Wc + bc ), Wc [64x3] ----
__global__ void k_head(const float* __restrict__ gsum, const float* __restrict__ gcnt,
                       const float* __restrict__ Wc, const float* __restrict__ bc,
                       float* __restrict__ out) {
    int g = threadIdx.x;
    if (g >= NGRAPH) return;
    float inv = 1.0f / fmaxf(gcnt[g], 1.0f);
    float l0 = bc[0], l1 = bc[1], l2 = bc[2];
#pragma unroll
    for (int k = 0; k < 64; ++k) {
        float m = gsum[g * 64 + k] * inv;
        l0 = fmaf(m, Wc[k * 3 + 0], l0);
        l1 = fmaf(m, Wc[k * 3 + 1], l1);
        l2 = fmaf(m, Wc[k * 3 + 2], l2);
    }
    float mx = fmaxf(l0, fmaxf(l1, l2));
    float e0 = expf(l0 - mx), e1 = expf(l1 - mx), e2 = expf(l2 - mx);
    float s = e0 + e1 + e2;
    out[g * 3 + 0] = e0 / s;
    out[g * 3 + 1] = e1 / s;
    out[g * 3 + 2] = e2 / s;
}

extern "C" void kernel_launch(void* const* d_in, const int* in_sizes, int n_in,
                              void* d_out, int out_size, void* d_ws, size_t ws_size,
                              hipStream_t stream) {
    const float* x     = (const float*)d_in[0];
    const int*   ei    = (const int*)d_in[1];
    const int*   batch = (const int*)d_in[2];
    const float* W1    = (const float*)d_in[3];
    const float* b1    = (const float*)d_in[4];
    const float* W2    = (const float*)d_in[5];
    const float* b2    = (const float*)d_in[6];
    const float* Wl    = (const float*)d_in[7];
    const float* bl    = (const float*)d_in[8];
    float* out = (float*)d_out;

    int nN = in_sizes[2];
    int nE = in_sizes[1] / 2;
    const int* srcp = ei;
    const int* dstp = ei + nE;

    int NBUCK = (nN + 255) >> 8;          // 391
    int L = NBUCK * NB1;                   // 100096
    int nB = (L + SCAN_B - 1) / SCAN_B;    // 25

    char* ws = (char*)d_ws;
    size_t off = 0;
    auto alloc = [&](size_t bytes) -> void* {
        void* p = ws + off;
        off += (bytes + 255) & ~(size_t)255;
        return p;
    };
    float* dinv    = (float*)alloc((size_t)nN * 4);
    int*   rowptr  = (int*)alloc(((size_t)nN + 1) * 4);
    int*   hist    = (int*)alloc((size_t)L * 4);
    int*   scanned = (int*)alloc((size_t)L * 4);
    int*   bsums   = (int*)alloc(256 * 4);
    u32*   staged  = (u32*)alloc((size_t)nE * 4);
    int*   esrc    = (int*)alloc((size_t)nE * 4);
    u32*   Hbf     = (u32*)alloc((size_t)nN * 32 * 4);   // bf16-packed [nN][64]
    u32*   Ybf     = (u32*)alloc((size_t)nN * 32 * 4);
    float* Z       = (float*)alloc((size_t)nN * 64 * 4);
    float* gsum    = (float*)alloc(NGRAPH * 64 * 4);
    float* gcnt    = (float*)alloc(NGRAPH * 4);
    float* Wc      = (float*)alloc(64 * 3 * 4);
    float* bc      = (float*)alloc(3 * 4);

    hipMemsetAsync(gsum, 0, NGRAPH * 64 * 4, stream);
    hipMemsetAsync(gcnt, 0, NGRAPH * 4, stream);

    // h1 = x@W1 (bf16 rows)
    k_gemm_bf<<<1024, 256, 0, stream>>>(x, W1, Hbf, nN);

    // atomic-free CSR: hist -> scan -> partition -> per-bucket place
    k_hist<<<NB1, 256, 0, stream>>>(dstp, hist, nE, NBUCK);
    k_scanA<<<nB, SCAN_T, 0, stream>>>(hist, scanned, bsums, L);
    k_scanB_fold<<<1, 256, 0, stream>>>(bsums, nB, W2, b2, Wl, bl, Wc, bc);
    k_scanC<<<nB, SCAN_T, 0, stream>>>(scanned, bsums, L);
    k_partition<<<NB1, 256, 0, stream>>>(srcp, dstp, scanned, staged, nE, NBUCK);
    k_pass2<<<NBUCK, 256, 0, stream>>>(staged, scanned, dinv, rowptr, esrc, nN, nE, NBUCK);

    // layer 1: y1 = relu(gather(h1)+b1) -> Ybf (bf16)
    k_gather_bf<<<(nN + 15) / 16, 256, 0, stream>>>(
        rowptr, esrc, (const uint2*)Hbf, dinv, b1, (uint2*)Ybf, nullptr, nN, 1, 1, 1);
    // layer 2 (reordered): z = S*y1 -> Z (fp32); W2/b2 folded into head
    k_gather_bf<<<(nN + 15) / 16, 256, 0, stream>>>(
        rowptr, esrc, (const uint2*)Ybf, dinv, nullptr, nullptr, (float4*)Z, nN, 0, 0, 0);

    // pool z + folded head
    k_pool<<<(nN + 511) / 512, 256, 0, stream>>>(Z, batch, gsum, gcnt, nN);
    k_head<<<1, 64, 0, stream>>>(gsum, gcnt, Wc, bc, out);
}

// Round 6
// 199.417 us; speedup vs baseline: 14.9544x; 1.1810x over previous
//
#include <hip/hip_runtime.h>

// GridGNN: 2x GCNConv(64->64) + ReLU, global_mean_pool, Linear(64->3), softmax.
// N=100000 nodes, E=1600000 edges, G=64 graphs, F=64 feats.
// R1: CSR + gather (no fp32 atomics). 2982 -> 454 us.
// R2: 4-B edge records, gemm2 folded past pooling. -> 393 us.
// R3: head folded; gemm+count fused (fusion HURT: atomics lost TLP). -> 332 us.
// R4: atomic-free CSR (LDS radix, 391 buckets); bf16 feature rows. -> 235 us.
// R5: register-W GEMM (lane c owns W[:,c], LDS same-addr broadcast for x;
//     old gemm was barrier-bound at 23% VALU, 52us); scanC folded into
//     partition/pass2; memsets merged.

typedef unsigned int u32;

#define NGRAPH 64
#define SCAN_T 256
#define SCAN_E 16
#define SCAN_B 4096
#define NB1 256  // blocks in hist/partition passes
#define GR 32    // rows per gemm tile (100000 % 32 == 0)

// ---- bf16 helpers (RN pack, exact unpack) ----
__device__ __forceinline__ float bflo(u32 v) { return __uint_as_float(v << 16); }
__device__ __forceinline__ float bfhi(u32 v) { return __uint_as_float(v & 0xffff0000u); }
__device__ __forceinline__ u32 packbf(float a, float b) {
    u32 ua = __float_as_uint(a); ua += 0x7fff + ((ua >> 16) & 1);
    u32 ub = __float_as_uint(b); ub += 0x7fff + ((ub >> 16) & 1);
    return (ua >> 16) | ((ub >> 16) << 16);
}

// ---- gemm: Out(bf16 packed) = X @ W. Lane c holds W[:,c] in 64 VGPRs.
//      x rows staged in LDS, read as same-address float4 broadcasts. ----
__global__ void k_gemm_reg(const float* __restrict__ X, const float* __restrict__ W,
                           u32* __restrict__ Out, int nRows) {
    __shared__ float xs[GR][64];
    int tid = threadIdx.x;      // 256
    int lane = tid & 63;        // output column
    int wv = tid >> 6;          // wave 0..3
    float wreg[64];
#pragma unroll
    for (int k = 0; k < 64; ++k) wreg[k] = W[k * 64 + lane];
    for (int t0 = blockIdx.x * GR; t0 < nRows; t0 += gridDim.x * GR) {
        __syncthreads();
        {   // stage GR rows: 512 float4 across 256 threads
            const float4* X4 = (const float4*)(X + (size_t)t0 * 64);
            float4 v0 = X4[tid];
            float4 v1 = X4[tid + 256];
            ((float4*)&xs[0][0])[tid] = v0;
            ((float4*)&xs[0][0])[tid + 256] = v1;
        }
        __syncthreads();
        // wave wv owns rows [wv*8, wv*8+8), 4 interleaved at a time
#pragma unroll
        for (int rr = 0; rr < 8; rr += 4) {
            int r = wv * 8 + rr;
            float a0 = 0.f, a1 = 0.f, a2 = 0.f, a3 = 0.f;
#pragma unroll
            for (int k4 = 0; k4 < 16; ++k4) {
                float4 x0 = *(const float4*)&xs[r + 0][k4 * 4];
                float4 x1 = *(const float4*)&xs[r + 1][k4 * 4];
                float4 x2 = *(const float4*)&xs[r + 2][k4 * 4];
                float4 x3 = *(const float4*)&xs[r + 3][k4 * 4];
                a0 = fmaf(x0.x, wreg[k4 * 4 + 0], a0);
                a1 = fmaf(x1.x, wreg[k4 * 4 + 0], a1);
                a2 = fmaf(x2.x, wreg[k4 * 4 + 0], a2);
                a3 = fmaf(x3.x, wreg[k4 * 4 + 0], a3);
                a0 = fmaf(x0.y, wreg[k4 * 4 + 1], a0);
                a1 = fmaf(x1.y, wreg[k4 * 4 + 1], a1);
                a2 = fmaf(x2.y, wreg[k4 * 4 + 1], a2);
                a3 = fmaf(x3.y, wreg[k4 * 4 + 1], a3);
                a0 = fmaf(x0.z, wreg[k4 * 4 + 2], a0);
                a1 = fmaf(x1.z, wreg[k4 * 4 + 2], a1);
                a2 = fmaf(x2.z, wreg[k4 * 4 + 2], a2);
                a3 = fmaf(x3.z, wreg[k4 * 4 + 2], a3);
                a0 = fmaf(x0.w, wreg[k4 * 4 + 3], a0);
                a1 = fmaf(x1.w, wreg[k4 * 4 + 3], a1);
                a2 = fmaf(x2.w, wreg[k4 * 4 + 3], a2);
                a3 = fmaf(x3.w, wreg[k4 * 4 + 3], a3);
            }
            float o0 = __shfl_xor(a0, 1);
            float o1 = __shfl_xor(a1, 1);
            float o2 = __shfl_xor(a2, 1);
            float o3 = __shfl_xor(a3, 1);
            if (!(lane & 1)) {
                int h = lane >> 1;
                Out[(size_t)(t0 + r + 0) * 32 + h] = packbf(a0, o0);
                Out[(size_t)(t0 + r + 1) * 32 + h] = packbf(a1, o1);
                Out[(size_t)(t0 + r + 2) * 32 + h] = packbf(a2, o2);
                Out[(size_t)(t0 + r + 3) * 32 + h] = packbf(a3, o3);
            }
        }
    }
}

// ---- pass 1a: per-block LDS histogram over dst>>8 -> histT[bucket*NB1+block] ----
__global__ void k_hist(const int* __restrict__ dst, int* __restrict__ histT,
                       int nE, int NBUCK) {
    __shared__ int h[512];
    int tid = threadIdx.x;
    for (int k = tid; k < NBUCK; k += 256) h[k] = 0;
    __syncthreads();
    int i = blockIdx.x * 256 + tid, stride = NB1 * 256;
    for (; i < nE; i += stride) atomicAdd(&h[dst[i] >> 8], 1);
    __syncthreads();
    for (int k = tid; k < NBUCK; k += 256) histT[k * NB1 + blockIdx.x] = h[k];
}

// ---- scan stage A: per-block exclusive scan of arr[L] -> out (scan-block local),
//      block totals -> bsums ----
__global__ void k_scanA(const int* __restrict__ arr, int* __restrict__ outp,
                        int* __restrict__ bsums, int L) {
    __shared__ int sh[SCAN_T];
    int b = blockIdx.x, tid = threadIdx.x;
    int base = b * SCAN_B + tid * SCAN_E;
    int v[SCAN_E];
    int s = 0;
#pragma unroll
    for (int j = 0; j < SCAN_E; ++j) {
        int idx = base + j;
        int c = (idx < L) ? arr[idx] : 0;
        v[j] = s;
        s += c;
    }
    sh[tid] = s;
    __syncthreads();
    for (int off = 1; off < SCAN_T; off <<= 1) {
        int t = (tid >= off) ? sh[tid - off] : 0;
        __syncthreads();
        sh[tid] += t;
        __syncthreads();
    }
    int excl = (tid == 0) ? 0 : sh[tid - 1];
    if (tid == SCAN_T - 1) bsums[b] = sh[tid];
#pragma unroll
    for (int j = 0; j < SCAN_E; ++j) {
        int idx = base + j;
        if (idx < L) outp[idx] = excl + v[j];
    }
}

// ---- scan stage B (1 block): serial scan of block sums on t0; idle lanes
//      fold head weights: Wc = W2@Wl [64x3], bc = b2@Wl + bl [3] ----
__global__ void k_scanB_fold(int* __restrict__ bsums, int nB,
                             const float* __restrict__ W2, const float* __restrict__ b2,
                             const float* __restrict__ Wl, const float* __restrict__ bl,
                             float* __restrict__ Wc, float* __restrict__ bc) {
    int tid = threadIdx.x;
    if (tid == 0) {
        int run = 0;
        for (int i = 0; i < nB; ++i) {
            int t = bsums[i];
            bsums[i] = run;
            run += t;
        }
    } else if (tid >= 64 && tid < 64 + 192) {
        int i = tid - 64;
        int k = i / 3, j = i % 3;
        float acc = 0.f;
#pragma unroll
        for (int c = 0; c < 64; ++c) acc = fmaf(W2[k * 64 + c], Wl[c * 3 + j], acc);
        Wc[k * 3 + j] = acc;
    } else if (tid >= 1 && tid <= 3) {
        int j = tid - 1;
        float acc = bl[j];
#pragma unroll
        for (int c = 0; c < 64; ++c) acc = fmaf(b2[c], Wl[c * 3 + j], acc);
        bc[j] = acc;
    }
}

// ---- pass 1c: partition edges into buckets via LDS cursors; scanC folded in ----
// staged[pos] = src | (dst&255)<<20   (src < 2^20)
__global__ void k_partition(const int* __restrict__ src, const int* __restrict__ dst,
                            const int* __restrict__ scanned, const int* __restrict__ bsums,
                            u32* __restrict__ staged, int nE, int NBUCK) {
    __shared__ int cur[512];
    int tid = threadIdx.x;
    for (int k = tid; k < NBUCK; k += 256) {
        int idx = k * NB1 + blockIdx.x;
        cur[k] = scanned[idx] + bsums[idx >> 12];
    }
    __syncthreads();
    int i = blockIdx.x * 256 + tid, stride = NB1 * 256;
    for (; i < nE; i += stride) {
        int d = dst[i];
        int k = d >> 8;
        int pos = atomicAdd(&cur[k], 1);
        staged[pos] = (u32)src[i] | ((u32)(d & 255) << 20);
    }
}

// ---- pass 2: per-bucket (256 dst) LDS count+scan+place -> esrc, rowptr, dinv ----
__global__ void k_pass2(const u32* __restrict__ staged, const int* __restrict__ scanned,
                        const int* __restrict__ bsums,
                        float* __restrict__ dinv, int* __restrict__ rowptr,
                        int* __restrict__ esrc, int nN, int nE, int NBUCK) {
    __shared__ int cnt[256], cur[256], sh[256];
    int bk = blockIdx.x, tid = threadIdx.x;
    int i0 = bk * NB1;
    int base = scanned[i0] + bsums[i0 >> 12];
    int end = nE;
    if (bk + 1 < NBUCK) {
        int i1 = (bk + 1) * NB1;
        end = scanned[i1] + bsums[i1 >> 12];
    }
    cnt[tid] = 0;
    __syncthreads();
    for (int e = base + tid; e < end; e += 256) atomicAdd(&cnt[staged[e] >> 20], 1);
    __syncthreads();
    int v = cnt[tid];
    sh[tid] = v;
    __syncthreads();
    for (int off = 1; off < 256; off <<= 1) {
        int t = (tid >= off) ? sh[tid - off] : 0;
        __syncthreads();
        sh[tid] += t;
        __syncthreads();
    }
    int excl = sh[tid] - v;
    int node = bk * 256 + tid;
    if (node < nN) {
        rowptr[node] = base + excl;
        dinv[node] = rsqrtf(1.0f + (float)v);
    }
    cur[tid] = excl;
    __syncthreads();
    for (int e = base + tid; e < end; e += 256) {
        u32 r = staged[e];
        int j = r >> 20;
        int pos = atomicAdd(&cur[j], 1);
        esrc[base + pos] = (int)(r & 0xFFFFFu);
    }
    if (bk == 0 && tid == 0) rowptr[nN] = nE;
}

// ---- fused gather (bf16 rows, fp32 accum) + self-loop (+bias)(+ReLU) ----
__global__ void k_gather_bf(const int* __restrict__ rowptr, const int* __restrict__ esrc,
                            const uint2* __restrict__ H, const float* __restrict__ dinv,
                            const float* __restrict__ bias, uint2* __restrict__ Obf,
                            float4* __restrict__ Of, int nN, int relu, int addb, int outbf) {
    int node = blockIdx.x * 16 + (threadIdx.x >> 4);
    int lane = threadIdx.x & 15;
    if (node >= nN) return;
    int e0 = rowptr[node], e1 = rowptr[node + 1];
    float4 acc = make_float4(0.f, 0.f, 0.f, 0.f);
#define GSTEP(s, cc) { uint2 v = H[(size_t)(s) * 16 + lane]; \
        acc.x = fmaf(cc, bflo(v.x), acc.x); acc.y = fmaf(cc, bfhi(v.x), acc.y); \
        acc.z = fmaf(cc, bflo(v.y), acc.z); acc.w = fmaf(cc, bfhi(v.y), acc.w); }
    int e = e0;
    for (; e + 3 < e1; e += 4) {
        int s0 = esrc[e], s1 = esrc[e + 1], s2 = esrc[e + 2], s3 = esrc[e + 3];
        float c0 = dinv[s0], c1 = dinv[s1], c2 = dinv[s2], c3 = dinv[s3];
        GSTEP(s0, c0) GSTEP(s1, c1) GSTEP(s2, c2) GSTEP(s3, c3)
    }
    for (; e < e1; ++e) {
        int s = esrc[e];
        float c = dinv[s];
        GSTEP(s, c)
    }
#undef GSTEP
    float di = dinv[node];
    uint2 hv = H[(size_t)node * 16 + lane];
    float x0 = di * fmaf(di, bflo(hv.x), acc.x);
    float x1 = di * fmaf(di, bfhi(hv.x), acc.y);
    float x2 = di * fmaf(di, bflo(hv.y), acc.z);
    float x3 = di * fmaf(di, bfhi(hv.y), acc.w);
    if (addb) {
        float4 bb = ((const float4*)bias)[lane];
        x0 += bb.x; x1 += bb.y; x2 += bb.z; x3 += bb.w;
    }
    if (relu) {
        x0 = fmaxf(x0, 0.f); x1 = fmaxf(x1, 0.f);
        x2 = fmaxf(x2, 0.f); x3 = fmaxf(x3, 0.f);
    }
    if (outbf) Obf[(size_t)node * 16 + lane] = make_uint2(packbf(x0, x1), packbf(x2, x3));
    else       Of[(size_t)node * 16 + lane] = make_float4(x0, x1, x2, x3);
}

// ---- pooled sums + counts; batch is sorted, so flush on graph-id change ----
__global__ void k_pool(const float* __restrict__ Y, const int* __restrict__ batch,
                       float* __restrict__ gsum, float* __restrict__ gcnt, int nN) {
    const int CH = 512;
    int n0 = blockIdx.x * CH;
    int f = threadIdx.x & 63, rl = threadIdx.x >> 6;
    int nend = n0 + CH; if (nend > nN) nend = nN;
    int curg = -1;
    float acc = 0.f, cacc = 0.f;
    for (int n = n0 + rl; n < nend; n += 4) {
        int g = batch[n];
        if (g != curg) {
            if (curg >= 0) {
                unsafeAtomicAdd(&gsum[curg * 64 + f], acc);
                if (f == 0) unsafeAtomicAdd(&gcnt[curg], cacc);
            }
            curg = g; acc = 0.f; cacc = 0.f;
        }
        acc += Y[(size_t)n * 64 + f];
        cacc += 1.f;
    }
    if (curg >= 0) {
        unsafeAtomicAdd(&gsum[curg * 64 + f], acc);
        if (f == 0) unsafeAtomicAdd(&gcnt[curg], cacc);
    }
}

// ---- head: out[g] = softmax( mean_g @ Wc + bc ), Wc [64x3] ----
__global__ void k_head(const float* __restrict__ gsum, const float* __restrict__ gcnt,
                       const float* __restrict__ Wc, const float* __restrict__ bc,
                       float* __restrict__ out) {
    int g = threadIdx.x;
    if (g >= NGRAPH) return;
    float inv = 1.0f / fmaxf(gcnt[g], 1.0f);
    float l0 = bc[0], l1 = bc[1], l2 = bc[2];
#pragma unroll
    for (int k = 0; k < 64; ++k) {
        float m = gsum[g * 64 + k] * inv;
        l0 = fmaf(m, Wc[k * 3 + 0], l0);
        l1 = fmaf(m, Wc[k * 3 + 1], l1);
        l2 = fmaf(m, Wc[k * 3 + 2], l2);
    }
    float mx = fmaxf(l0, fmaxf(l1, l2));
    float e0 = expf(l0 - mx), e1 = expf(l1 - mx), e2 = expf(l2 - mx);
    float s = e0 + e1 + e2;
    out[g * 3 + 0] = e0 / s;
    out[g * 3 + 1] = e1 / s;
    out[g * 3 + 2] = e2 / s;
}

extern "C" void kernel_launch(void* const* d_in, const int* in_sizes, int n_in,
                              void* d_out, int out_size, void* d_ws, size_t ws_size,
                              hipStream_t stream) {
    const float* x     = (const float*)d_in[0];
    const int*   ei    = (const int*)d_in[1];
    const int*   batch = (const int*)d_in[2];
    const float* W1    = (const float*)d_in[3];
    const float* b1    = (const float*)d_in[4];
    const float* W2    = (const float*)d_in[5];
    const float* b2    = (const float*)d_in[6];
    const float* Wl    = (const float*)d_in[7];
    const float* bl    = (const float*)d_in[8];
    float* out = (float*)d_out;

    int nN = in_sizes[2];
    int nE = in_sizes[1] / 2;
    const int* srcp = ei;
    const int* dstp = ei + nE;

    int NBUCK = (nN + 255) >> 8;          // 391
    int L = NBUCK * NB1;                   // 100096
    int nB = (L + SCAN_B - 1) / SCAN_B;    // 25

    char* ws = (char*)d_ws;
    size_t off = 0;
    auto alloc = [&](size_t bytes) -> void* {
        void* p = ws + off;
        off += (bytes + 255) & ~(size_t)255;
        return p;
    };
    float* dinv    = (float*)alloc((size_t)nN * 4);
    int*   rowptr  = (int*)alloc(((size_t)nN + 1) * 4);
    int*   hist    = (int*)alloc((size_t)L * 4);
    int*   scanned = (int*)alloc((size_t)L * 4);
    int*   bsums   = (int*)alloc(256 * 4);
    u32*   staged  = (u32*)alloc((size_t)nE * 4);
    int*   esrc    = (int*)alloc((size_t)nE * 4);
    u32*   Hbf     = (u32*)alloc((size_t)nN * 32 * 4);   // bf16-packed [nN][64]
    u32*   Ybf     = (u32*)alloc((size_t)nN * 32 * 4);
    float* Z       = (float*)alloc((size_t)nN * 64 * 4);
    float* gsum    = (float*)alloc(NGRAPH * 64 * 4);     // gcnt directly follows
    float* gcnt    = (float*)alloc(NGRAPH * 4);
    float* Wc      = (float*)alloc(64 * 3 * 4);
    float* bc      = (float*)alloc(3 * 4);

    // one memset covers gsum (16384 B, 256-aligned) + gcnt (256 B slot)
    hipMemsetAsync(gsum, 0, NGRAPH * 64 * 4 + 256, stream);

    // h1 = x@W1 (bf16 rows)
    k_gemm_reg<<<1024, 256, 0, stream>>>(x, W1, Hbf, nN);

    // atomic-free CSR: hist -> scan -> partition -> per-bucket place
    k_hist<<<NB1, 256, 0, stream>>>(dstp, hist, nE, NBUCK);
    k_scanA<<<nB, SCAN_T, 0, stream>>>(hist, scanned, bsums, L);
    k_scanB_fold<<<1, 256, 0, stream>>>(bsums, nB, W2, b2, Wl, bl, Wc, bc);
    k_partition<<<NB1, 256, 0, stream>>>(srcp, dstp, scanned, bsums, staged, nE, NBUCK);
    k_pass2<<<NBUCK, 256, 0, stream>>>(staged, scanned, bsums, dinv, rowptr, esrc, nN, nE, NBUCK);

    // layer 1: y1 = relu(gather(h1)+b1) -> Ybf (bf16)
    k_gather_bf<<<(nN + 15) / 16, 256, 0, stream>>>(
        rowptr, esrc, (const uint2*)Hbf, dinv, b1, (uint2*)Ybf, nullptr, nN, 1, 1, 1);
    // layer 2 (reordered): z = S*y1 -> Z (fp32); W2/b2 folded into head
    k_gather_bf<<<(nN + 15) / 16, 256, 0, stream>>>(
        rowptr, esrc, (const uint2*)Ybf, dinv, nullptr, nullptr, (float4*)Z, nN, 0, 0, 0);

    // pool z + folded head
    k_pool<<<(nN + 511) / 512, 256, 0, stream>>>(Z, batch, gsum, gcnt, nN);
    k_head<<<1, 64, 0, stream>>>(gsum, gcnt, Wc, bc, out);
}

// Round 7
// 176.870 us; speedup vs baseline: 16.8607x; 1.1275x over previous
//
#include <hip/hip_runtime.h>

// GridGNN: 2x GCNConv(64->64) + ReLU, global_mean_pool, Linear(64->3), softmax.
// N=100000 nodes, E=1600000 edges, G=64 graphs, F=64 feats.
// R1: CSR + gather (no fp32 atomics). 2982 -> 454 us.
// R2: 4-B edge records, gemm2 folded past pooling. -> 393 us.
// R3: head folded; gemm+count fused (fusion HURT: atomics lost TLP). -> 332 us.
// R4: atomic-free CSR (LDS radix, 391 buckets); bf16 feature rows. -> 235 us.
// R5: register-W GEMM; scanC folded into partition/pass2. -> 199 us.
// R6: pool rebuilt (was 47us latency-bound at 7% occupancy: 196 blocks +
//     serial branchy loop) -> 1563 blocks, LDS batch, unrolled uniform-chunk
//     fast path; dinv prescaled into bf16 rows (hs = dinv*h) so gather inner
//     loop is pure row adds (no random dinv loads, no per-edge mul).

typedef unsigned int u32;

#define NGRAPH 64
#define SCAN_T 256
#define SCAN_E 16
#define SCAN_B 4096
#define NB1 256  // blocks in hist/partition passes
#define GR 32    // rows per gemm tile (100000 % 32 == 0)

// ---- bf16 helpers (RN pack, exact unpack) ----
__device__ __forceinline__ float bflo(u32 v) { return __uint_as_float(v << 16); }
__device__ __forceinline__ float bfhi(u32 v) { return __uint_as_float(v & 0xffff0000u); }
__device__ __forceinline__ u32 packbf(float a, float b) {
    u32 ua = __float_as_uint(a); ua += 0x7fff + ((ua >> 16) & 1);
    u32 ub = __float_as_uint(b); ub += 0x7fff + ((ub >> 16) & 1);
    return (ua >> 16) | ((ub >> 16) << 16);
}

// ---- gemm: Out(bf16) = dinv[r] * (X @ W). Lane c holds W[:,c] in 64 VGPRs. ----
__global__ void k_gemm_reg(const float* __restrict__ X, const float* __restrict__ W,
                           const float* __restrict__ dinv, u32* __restrict__ Out,
                           int nRows) {
    __shared__ float xs[GR][64];
    int tid = threadIdx.x;      // 256
    int lane = tid & 63;        // output column
    int wv = tid >> 6;          // wave 0..3
    float wreg[64];
#pragma unroll
    for (int k = 0; k < 64; ++k) wreg[k] = W[k * 64 + lane];
    for (int t0 = blockIdx.x * GR; t0 < nRows; t0 += gridDim.x * GR) {
        __syncthreads();
        {   // stage GR rows: 512 float4 across 256 threads
            const float4* X4 = (const float4*)(X + (size_t)t0 * 64);
            float4 v0 = X4[tid];
            float4 v1 = X4[tid + 256];
            ((float4*)&xs[0][0])[tid] = v0;
            ((float4*)&xs[0][0])[tid + 256] = v1;
        }
        __syncthreads();
#pragma unroll
        for (int rr = 0; rr < 8; rr += 4) {
            int r = wv * 8 + rr;
            float a0 = 0.f, a1 = 0.f, a2 = 0.f, a3 = 0.f;
#pragma unroll
            for (int k4 = 0; k4 < 16; ++k4) {
                float4 x0 = *(const float4*)&xs[r + 0][k4 * 4];
                float4 x1 = *(const float4*)&xs[r + 1][k4 * 4];
                float4 x2 = *(const float4*)&xs[r + 2][k4 * 4];
                float4 x3 = *(const float4*)&xs[r + 3][k4 * 4];
                a0 = fmaf(x0.x, wreg[k4 * 4 + 0], a0);
                a1 = fmaf(x1.x, wreg[k4 * 4 + 0], a1);
                a2 = fmaf(x2.x, wreg[k4 * 4 + 0], a2);
                a3 = fmaf(x3.x, wreg[k4 * 4 + 0], a3);
                a0 = fmaf(x0.y, wreg[k4 * 4 + 1], a0);
                a1 = fmaf(x1.y, wreg[k4 * 4 + 1], a1);
                a2 = fmaf(x2.y, wreg[k4 * 4 + 1], a2);
                a3 = fmaf(x3.y, wreg[k4 * 4 + 1], a3);
                a0 = fmaf(x0.z, wreg[k4 * 4 + 2], a0);
                a1 = fmaf(x1.z, wreg[k4 * 4 + 2], a1);
                a2 = fmaf(x2.z, wreg[k4 * 4 + 2], a2);
                a3 = fmaf(x3.z, wreg[k4 * 4 + 2], a3);
                a0 = fmaf(x0.w, wreg[k4 * 4 + 3], a0);
                a1 = fmaf(x1.w, wreg[k4 * 4 + 3], a1);
                a2 = fmaf(x2.w, wreg[k4 * 4 + 3], a2);
                a3 = fmaf(x3.w, wreg[k4 * 4 + 3], a3);
            }
            // prescale by dinv[row]
            a0 *= dinv[t0 + r + 0];
            a1 *= dinv[t0 + r + 1];
            a2 *= dinv[t0 + r + 2];
            a3 *= dinv[t0 + r + 3];
            float o0 = __shfl_xor(a0, 1);
            float o1 = __shfl_xor(a1, 1);
            float o2 = __shfl_xor(a2, 1);
            float o3 = __shfl_xor(a3, 1);
            if (!(lane & 1)) {
                int h = lane >> 1;
                Out[(size_t)(t0 + r + 0) * 32 + h] = packbf(a0, o0);
                Out[(size_t)(t0 + r + 1) * 32 + h] = packbf(a1, o1);
                Out[(size_t)(t0 + r + 2) * 32 + h] = packbf(a2, o2);
                Out[(size_t)(t0 + r + 3) * 32 + h] = packbf(a3, o3);
            }
        }
    }
}

// ---- pass 1a: per-block LDS histogram over dst>>8 -> histT[bucket*NB1+block] ----
__global__ void k_hist(const int* __restrict__ dst, int* __restrict__ histT,
                       int nE, int NBUCK) {
    __shared__ int h[512];
    int tid = threadIdx.x;
    for (int k = tid; k < NBUCK; k += 256) h[k] = 0;
    __syncthreads();
    int i = blockIdx.x * 256 + tid, stride = NB1 * 256;
    for (; i < nE; i += stride) atomicAdd(&h[dst[i] >> 8], 1);
    __syncthreads();
    for (int k = tid; k < NBUCK; k += 256) histT[k * NB1 + blockIdx.x] = h[k];
}

// ---- scan stage A ----
__global__ void k_scanA(const int* __restrict__ arr, int* __restrict__ outp,
                        int* __restrict__ bsums, int L) {
    __shared__ int sh[SCAN_T];
    int b = blockIdx.x, tid = threadIdx.x;
    int base = b * SCAN_B + tid * SCAN_E;
    int v[SCAN_E];
    int s = 0;
#pragma unroll
    for (int j = 0; j < SCAN_E; ++j) {
        int idx = base + j;
        int c = (idx < L) ? arr[idx] : 0;
        v[j] = s;
        s += c;
    }
    sh[tid] = s;
    __syncthreads();
    for (int off = 1; off < SCAN_T; off <<= 1) {
        int t = (tid >= off) ? sh[tid - off] : 0;
        __syncthreads();
        sh[tid] += t;
        __syncthreads();
    }
    int excl = (tid == 0) ? 0 : sh[tid - 1];
    if (tid == SCAN_T - 1) bsums[b] = sh[tid];
#pragma unroll
    for (int j = 0; j < SCAN_E; ++j) {
        int idx = base + j;
        if (idx < L) outp[idx] = excl + v[j];
    }
}

// ---- scan stage B (1 block) + head-weight folding on idle lanes ----
__global__ void k_scanB_fold(int* __restrict__ bsums, int nB,
                             const float* __restrict__ W2, const float* __restrict__ b2,
                             const float* __restrict__ Wl, const float* __restrict__ bl,
                             float* __restrict__ Wc, float* __restrict__ bc) {
    int tid = threadIdx.x;
    if (tid == 0) {
        int run = 0;
        for (int i = 0; i < nB; ++i) {
            int t = bsums[i];
            bsums[i] = run;
            run += t;
        }
    } else if (tid >= 64 && tid < 64 + 192) {
        int i = tid - 64;
        int k = i / 3, j = i % 3;
        float acc = 0.f;
#pragma unroll
        for (int c = 0; c < 64; ++c) acc = fmaf(W2[k * 64 + c], Wl[c * 3 + j], acc);
        Wc[k * 3 + j] = acc;
    } else if (tid >= 1 && tid <= 3) {
        int j = tid - 1;
        float acc = bl[j];
#pragma unroll
        for (int c = 0; c < 64; ++c) acc = fmaf(b2[c], Wl[c * 3 + j], acc);
        bc[j] = acc;
    }
}

// ---- pass 1c: partition edges into buckets via LDS cursors ----
__global__ void k_partition(const int* __restrict__ src, const int* __restrict__ dst,
                            const int* __restrict__ scanned, const int* __restrict__ bsums,
                            u32* __restrict__ staged, int nE, int NBUCK) {
    __shared__ int cur[512];
    int tid = threadIdx.x;
    for (int k = tid; k < NBUCK; k += 256) {
        int idx = k * NB1 + blockIdx.x;
        cur[k] = scanned[idx] + bsums[idx >> 12];
    }
    __syncthreads();
    int i = blockIdx.x * 256 + tid, stride = NB1 * 256;
    for (; i < nE; i += stride) {
        int d = dst[i];
        int k = d >> 8;
        int pos = atomicAdd(&cur[k], 1);
        staged[pos] = (u32)src[i] | ((u32)(d & 255) << 20);
    }
}

// ---- pass 2: per-bucket LDS count+scan+place -> esrc, rowptr, dinv ----
__global__ void k_pass2(const u32* __restrict__ staged, const int* __restrict__ scanned,
                        const int* __restrict__ bsums,
                        float* __restrict__ dinv, int* __restrict__ rowptr,
                        int* __restrict__ esrc, int nN, int nE, int NBUCK) {
    __shared__ int cnt[256], cur[256], sh[256];
    int bk = blockIdx.x, tid = threadIdx.x;
    int i0 = bk * NB1;
    int base = scanned[i0] + bsums[i0 >> 12];
    int end = nE;
    if (bk + 1 < NBUCK) {
        int i1 = (bk + 1) * NB1;
        end = scanned[i1] + bsums[i1 >> 12];
    }
    cnt[tid] = 0;
    __syncthreads();
    for (int e = base + tid; e < end; e += 256) atomicAdd(&cnt[staged[e] >> 20], 1);
    __syncthreads();
    int v = cnt[tid];
    sh[tid] = v;
    __syncthreads();
    for (int off = 1; off < 256; off <<= 1) {
        int t = (tid >= off) ? sh[tid - off] : 0;
        __syncthreads();
        sh[tid] += t;
        __syncthreads();
    }
    int excl = sh[tid] - v;
    int node = bk * 256 + tid;
    if (node < nN) {
        rowptr[node] = base + excl;
        dinv[node] = rsqrtf(1.0f + (float)v);
    }
    cur[tid] = excl;
    __syncthreads();
    for (int e = base + tid; e < end; e += 256) {
        u32 r = staged[e];
        int j = r >> 20;
        int pos = atomicAdd(&cur[j], 1);
        esrc[base + pos] = (int)(r & 0xFFFFFu);
    }
    if (bk == 0 && tid == 0) rowptr[nN] = nE;
}

// ---- fused gather of prescaled bf16 rows + self + (bias,relu,outscale) ----
// pre = dinv[d]*( sum_{s in N(d)} H[s] + H[d] ) (+bias)(relu)
// outbf: write packbf(dinv[d]*pre) ; else write fp32 pre
__global__ void k_gather_bf(const int* __restrict__ rowptr, const int* __restrict__ esrc,
                            const uint2* __restrict__ H, const float* __restrict__ dinv,
                            const float* __restrict__ bias, uint2* __restrict__ Obf,
                            float4* __restrict__ Of, int nN, int relu, int addb, int outbf) {
    int node = blockIdx.x * 16 + (threadIdx.x >> 4);
    int lane = threadIdx.x & 15;
    if (node >= nN) return;
    int e0 = rowptr[node], e1 = rowptr[node + 1];
    float4 acc = make_float4(0.f, 0.f, 0.f, 0.f);
#define GSTEP(s) { uint2 v = H[(size_t)(s) * 16 + lane]; \
        acc.x += bflo(v.x); acc.y += bfhi(v.x); \
        acc.z += bflo(v.y); acc.w += bfhi(v.y); }
    int e = e0;
    for (; e + 3 < e1; e += 4) {
        int s0 = esrc[e], s1 = esrc[e + 1], s2 = esrc[e + 2], s3 = esrc[e + 3];
        GSTEP(s0) GSTEP(s1) GSTEP(s2) GSTEP(s3)
    }
    for (; e < e1; ++e) {
        int s = esrc[e];
        GSTEP(s)
    }
#undef GSTEP
    float di = dinv[node];
    uint2 hv = H[(size_t)node * 16 + lane];
    float x0 = di * (acc.x + bflo(hv.x));
    float x1 = di * (acc.y + bfhi(hv.x));
    float x2 = di * (acc.z + bflo(hv.y));
    float x3 = di * (acc.w + bfhi(hv.y));
    if (addb) {
        float4 bb = ((const float4*)bias)[lane];
        x0 += bb.x; x1 += bb.y; x2 += bb.z; x3 += bb.w;
    }
    if (relu) {
        x0 = fmaxf(x0, 0.f); x1 = fmaxf(x1, 0.f);
        x2 = fmaxf(x2, 0.f); x3 = fmaxf(x3, 0.f);
    }
    if (outbf) {
        Obf[(size_t)node * 16 + lane] =
            make_uint2(packbf(di * x0, di * x1), packbf(di * x2, di * x3));
    } else {
        Of[(size_t)node * 16 + lane] = make_float4(x0, x1, x2, x3);
    }
}

// ---- pool: CH=64 nodes/block; LDS batch; unrolled fast path for uniform chunks ----
__global__ void k_pool(const float* __restrict__ Y, const int* __restrict__ batch,
                       float* __restrict__ gsum, float* __restrict__ gcnt, int nN) {
    const int CH = 64;
    __shared__ int bsh[CH];
    __shared__ float red[4][64];
    int n0 = blockIdx.x * CH;
    int tid = threadIdx.x;
    int f = tid & 63, rl = tid >> 6;
    int nend = n0 + CH; if (nend > nN) nend = nN;
    int cnt = nend - n0;
    if (cnt <= 0) return;
    if (tid < CH) bsh[tid] = (n0 + tid < nN) ? batch[n0 + tid] : -1;
    __syncthreads();
    int g0 = bsh[0];
    bool uniform = (cnt == CH) && (bsh[CH - 1] == g0);
    if (uniform) {
        const float* Yp = Y + (size_t)n0 * 64 + f;
        float acc = 0.f;
#pragma unroll
        for (int r = 0; r < 16; ++r) acc += Yp[(size_t)(rl + r * 4) * 64];
        red[rl][f] = acc;
        __syncthreads();
        if (rl == 0) {
            float s = red[0][f] + red[1][f] + red[2][f] + red[3][f];
            unsafeAtomicAdd(&gsum[g0 * 64 + f], s);
        }
    } else {
        int curg = -1; float acc = 0.f;
        for (int n = n0 + rl; n < nend; n += 4) {
            int g = bsh[n - n0];
            if (g != curg) {
                if (curg >= 0) unsafeAtomicAdd(&gsum[curg * 64 + f], acc);
                curg = g; acc = 0.f;
            }
            acc += Y[(size_t)n * 64 + f];
        }
        if (curg >= 0) unsafeAtomicAdd(&gsum[curg * 64 + f], acc);
    }
    // node counts: one thread walks the LDS batch chunk
    if (tid == 0) {
        int curg = bsh[0]; float c = 0.f;
        for (int i = 0; i < cnt; ++i) {
            if (bsh[i] != curg) {
                unsafeAtomicAdd(&gcnt[curg], c);
                curg = bsh[i]; c = 0.f;
            }
            c += 1.f;
        }
        unsafeAtomicAdd(&gcnt[curg], c);
    }
}

// ---- head: out[g] = softmax( mean_g @ Wc + bc ), Wc [64x3] ----
__global__ void k_head(const float* __restrict__ gsum, const float* __restrict__ gcnt,
                       const float* __restrict__ Wc, const float* __restrict__ bc,
                       float* __restrict__ out) {
    int g = threadIdx.x;
    if (g >= NGRAPH) return;
    float inv = 1.0f / fmaxf(gcnt[g], 1.0f);
    float l0 = bc[0], l1 = bc[1], l2 = bc[2];
#pragma unroll
    for (int k = 0; k < 64; ++k) {
        float m = gsum[g * 64 + k] * inv;
        l0 = fmaf(m, Wc[k * 3 + 0], l0);
        l1 = fmaf(m, Wc[k * 3 + 1], l1);
        l2 = fmaf(m, Wc[k * 3 + 2], l2);
    }
    float mx = fmaxf(l0, fmaxf(l1, l2));
    float e0 = expf(l0 - mx), e1 = expf(l1 - mx), e2 = expf(l2 - mx);
    float s = e0 + e1 + e2;
    out[g * 3 + 0] = e0 / s;
    out[g * 3 + 1] = e1 / s;
    out[g * 3 + 2] = e2 / s;
}

extern "C" void kernel_launch(void* const* d_in, const int* in_sizes, int n_in,
                              void* d_out, int out_size, void* d_ws, size_t ws_size,
                              hipStream_t stream) {
    const float* x     = (const float*)d_in[0];
    const int*   ei    = (const int*)d_in[1];
    const int*   batch = (const int*)d_in[2];
    const float* W1    = (const float*)d_in[3];
    const float* b1    = (const float*)d_in[4];
    const float* W2    = (const float*)d_in[5];
    const float* b2    = (const float*)d_in[6];
    const float* Wl    = (const float*)d_in[7];
    const float* bl    = (const float*)d_in[8];
    float* out = (float*)d_out;

    int nN = in_sizes[2];
    int nE = in_sizes[1] / 2;
    const int* srcp = ei;
    const int* dstp = ei + nE;

    int NBUCK = (nN + 255) >> 8;          // 391
    int L = NBUCK * NB1;                   // 100096
    int nB = (L + SCAN_B - 1) / SCAN_B;    // 25

    char* ws = (char*)d_ws;
    size_t off = 0;
    auto alloc = [&](size_t bytes) -> void* {
        void* p = ws + off;
        off += (bytes + 255) & ~(size_t)255;
        return p;
    };
    float* dinv    = (float*)alloc((size_t)nN * 4);
    int*   rowptr  = (int*)alloc(((size_t)nN + 1) * 4);
    int*   hist    = (int*)alloc((size_t)L * 4);
    int*   scanned = (int*)alloc((size_t)L * 4);
    int*   bsums   = (int*)alloc(256 * 4);
    u32*   staged  = (u32*)alloc((size_t)nE * 4);
    int*   esrc    = (int*)alloc((size_t)nE * 4);
    u32*   Hbf     = (u32*)alloc((size_t)nN * 32 * 4);   // bf16-packed [nN][64]
    u32*   Ybf     = (u32*)alloc((size_t)nN * 32 * 4);
    float* Z       = (float*)alloc((size_t)nN * 64 * 4);
    float* gsum    = (float*)alloc(NGRAPH * 64 * 4);     // gcnt directly follows
    float* gcnt   = (float*)alloc(NGRAPH * 4);
    float* Wc      = (float*)alloc(64 * 3 * 4);
    float* bc      = (float*)alloc(3 * 4);

    // one memset covers gsum (16384 B) + gcnt (256 B slot)
    hipMemsetAsync(gsum, 0, NGRAPH * 64 * 4 + 256, stream);

    // atomic-free CSR first (produces dinv for the prescaled GEMM)
    k_hist<<<NB1, 256, 0, stream>>>(dstp, hist, nE, NBUCK);
    k_scanA<<<nB, SCAN_T, 0, stream>>>(hist, scanned, bsums, L);
    k_scanB_fold<<<1, 256, 0, stream>>>(bsums, nB, W2, b2, Wl, bl, Wc, bc);
    k_partition<<<NB1, 256, 0, stream>>>(srcp, dstp, scanned, bsums, staged, nE, NBUCK);
    k_pass2<<<NBUCK, 256, 0, stream>>>(staged, scanned, bsums, dinv, rowptr, esrc, nN, nE, NBUCK);

    // hs = dinv * (x@W1), bf16 rows
    k_gemm_reg<<<1024, 256, 0, stream>>>(x, W1, dinv, Hbf, nN);

    // layer 1: ys1 = dinv * relu(gather(hs)+b1) -> Ybf (bf16)
    k_gather_bf<<<(nN + 15) / 16, 256, 0, stream>>>(
        rowptr, esrc, (const uint2*)Hbf, dinv, b1, (uint2*)Ybf, nullptr, nN, 1, 1, 1);
    // layer 2: z = dinv*(gather(ys1)+self) -> Z (fp32); W2/b2 folded into head
    k_gather_bf<<<(nN + 15) / 16, 256, 0, stream>>>(
        rowptr, esrc, (const uint2*)Ybf, dinv, nullptr, nullptr, (float4*)Z, nN, 0, 0, 0);

    // pool z + folded head
    k_pool<<<(nN + 63) / 64, 256, 0, stream>>>(Z, batch, gsum, gcnt, nN);
    k_head<<<1, 64, 0, stream>>>(gsum, gcnt, Wc, bc, out);
}

// Round 8
// 172.179 us; speedup vs baseline: 17.3201x; 1.0272x over previous
//
#include <hip/hip_runtime.h>

// GridGNN: 2x GCNConv(64->64) + ReLU, global_mean_pool, Linear(64->3), softmax.
// N=100000 nodes, E=1600000 edges, G=64 graphs, F=64 feats.
// R1: CSR + gather (no fp32 atomics). 2982 -> 454 us.
// R2: 4-B edge records, gemm2 folded past pooling. -> 393 us.
// R3: head folded; gemm+count fused (fusion HURT: atomics lost TLP). -> 332 us.
// R4: atomic-free CSR (LDS radix, 391 buckets); bf16 feature rows. -> 235 us.
// R5: register-W GEMM; scanC folded into partition/pass2. -> 199 us.
// R6: pool rebuilt (1563 blocks, LDS batch, uniform fast path); dinv
//     prescaled into bf16 rows. -> 177 us.
// R7: hipMemsetAsync removed (rocclr fillBuffer was 40us of pure dispatch
//     latency for 16KB!) -- gsum/gcnt zeroed inside k_hist block 0.

typedef unsigned int u32;

#define NGRAPH 64
#define SCAN_T 256
#define SCAN_E 16
#define SCAN_B 4096
#define NB1 256  // blocks in hist/partition passes
#define GR 32    // rows per gemm tile (100000 % 32 == 0)

// ---- bf16 helpers (RN pack, exact unpack) ----
__device__ __forceinline__ float bflo(u32 v) { return __uint_as_float(v << 16); }
__device__ __forceinline__ float bfhi(u32 v) { return __uint_as_float(v & 0xffff0000u); }
__device__ __forceinline__ u32 packbf(float a, float b) {
    u32 ua = __float_as_uint(a); ua += 0x7fff + ((ua >> 16) & 1);
    u32 ub = __float_as_uint(b); ub += 0x7fff + ((ub >> 16) & 1);
    return (ua >> 16) | ((ub >> 16) << 16);
}

// ---- gemm: Out(bf16) = dinv[r] * (X @ W). Lane c holds W[:,c] in 64 VGPRs. ----
__global__ void k_gemm_reg(const float* __restrict__ X, const float* __restrict__ W,
                           const float* __restrict__ dinv, u32* __restrict__ Out,
                           int nRows) {
    __shared__ float xs[GR][64];
    int tid = threadIdx.x;      // 256
    int lane = tid & 63;        // output column
    int wv = tid >> 6;          // wave 0..3
    float wreg[64];
#pragma unroll
    for (int k = 0; k < 64; ++k) wreg[k] = W[k * 64 + lane];
    for (int t0 = blockIdx.x * GR; t0 < nRows; t0 += gridDim.x * GR) {
        __syncthreads();
        {   // stage GR rows: 512 float4 across 256 threads
            const float4* X4 = (const float4*)(X + (size_t)t0 * 64);
            float4 v0 = X4[tid];
            float4 v1 = X4[tid + 256];
            ((float4*)&xs[0][0])[tid] = v0;
            ((float4*)&xs[0][0])[tid + 256] = v1;
        }
        __syncthreads();
#pragma unroll
        for (int rr = 0; rr < 8; rr += 4) {
            int r = wv * 8 + rr;
            float a0 = 0.f, a1 = 0.f, a2 = 0.f, a3 = 0.f;
#pragma unroll
            for (int k4 = 0; k4 < 16; ++k4) {
                float4 x0 = *(const float4*)&xs[r + 0][k4 * 4];
                float4 x1 = *(const float4*)&xs[r + 1][k4 * 4];
                float4 x2 = *(const float4*)&xs[r + 2][k4 * 4];
                float4 x3 = *(const float4*)&xs[r + 3][k4 * 4];
                a0 = fmaf(x0.x, wreg[k4 * 4 + 0], a0);
                a1 = fmaf(x1.x, wreg[k4 * 4 + 0], a1);
                a2 = fmaf(x2.x, wreg[k4 * 4 + 0], a2);
                a3 = fmaf(x3.x, wreg[k4 * 4 + 0], a3);
                a0 = fmaf(x0.y, wreg[k4 * 4 + 1], a0);
                a1 = fmaf(x1.y, wreg[k4 * 4 + 1], a1);
                a2 = fmaf(x2.y, wreg[k4 * 4 + 1], a2);
                a3 = fmaf(x3.y, wreg[k4 * 4 + 1], a3);
                a0 = fmaf(x0.z, wreg[k4 * 4 + 2], a0);
                a1 = fmaf(x1.z, wreg[k4 * 4 + 2], a1);
                a2 = fmaf(x2.z, wreg[k4 * 4 + 2], a2);
                a3 = fmaf(x3.z, wreg[k4 * 4 + 2], a3);
                a0 = fmaf(x0.w, wreg[k4 * 4 + 3], a0);
                a1 = fmaf(x1.w, wreg[k4 * 4 + 3], a1);
                a2 = fmaf(x2.w, wreg[k4 * 4 + 3], a2);
                a3 = fmaf(x3.w, wreg[k4 * 4 + 3], a3);
            }
            a0 *= dinv[t0 + r + 0];
            a1 *= dinv[t0 + r + 1];
            a2 *= dinv[t0 + r + 2];
            a3 *= dinv[t0 + r + 3];
            float o0 = __shfl_xor(a0, 1);
            float o1 = __shfl_xor(a1, 1);
            float o2 = __shfl_xor(a2, 1);
            float o3 = __shfl_xor(a3, 1);
            if (!(lane & 1)) {
                int h = lane >> 1;
                Out[(size_t)(t0 + r + 0) * 32 + h] = packbf(a0, o0);
                Out[(size_t)(t0 + r + 1) * 32 + h] = packbf(a1, o1);
                Out[(size_t)(t0 + r + 2) * 32 + h] = packbf(a2, o2);
                Out[(size_t)(t0 + r + 3) * 32 + h] = packbf(a3, o3);
            }
        }
    }
}

// ---- pass 1a: per-block LDS histogram over dst>>8 -> histT[bucket*NB1+block];
//      block 0 additionally zeroes gsum+gcnt (replaces 40us rocclr fill) ----
__global__ void k_hist(const int* __restrict__ dst, int* __restrict__ histT,
                       float* __restrict__ zbuf, int nZ, int nE, int NBUCK) {
    __shared__ int h[512];
    int tid = threadIdx.x;
    if (blockIdx.x == 0) {
        for (int i = tid; i < nZ; i += 256) zbuf[i] = 0.f;
    }
    for (int k = tid; k < NBUCK; k += 256) h[k] = 0;
    __syncthreads();
    int i = blockIdx.x * 256 + tid, stride = NB1 * 256;
    for (; i < nE; i += stride) atomicAdd(&h[dst[i] >> 8], 1);
    __syncthreads();
    for (int k = tid; k < NBUCK; k += 256) histT[k * NB1 + blockIdx.x] = h[k];
}

// ---- scan stage A ----
__global__ void k_scanA(const int* __restrict__ arr, int* __restrict__ outp,
                        int* __restrict__ bsums, int L) {
    __shared__ int sh[SCAN_T];
    int b = blockIdx.x, tid = threadIdx.x;
    int base = b * SCAN_B + tid * SCAN_E;
    int v[SCAN_E];
    int s = 0;
#pragma unroll
    for (int j = 0; j < SCAN_E; ++j) {
        int idx = base + j;
        int c = (idx < L) ? arr[idx] : 0;
        v[j] = s;
        s += c;
    }
    sh[tid] = s;
    __syncthreads();
    for (int off = 1; off < SCAN_T; off <<= 1) {
        int t = (tid >= off) ? sh[tid - off] : 0;
        __syncthreads();
        sh[tid] += t;
        __syncthreads();
    }
    int excl = (tid == 0) ? 0 : sh[tid - 1];
    if (tid == SCAN_T - 1) bsums[b] = sh[tid];
#pragma unroll
    for (int j = 0; j < SCAN_E; ++j) {
        int idx = base + j;
        if (idx < L) outp[idx] = excl + v[j];
    }
}

// ---- scan stage B (1 block) + head-weight folding on idle lanes ----
__global__ void k_scanB_fold(int* __restrict__ bsums, int nB,
                             const float* __restrict__ W2, const float* __restrict__ b2,
                             const float* __restrict__ Wl, const float* __restrict__ bl,
                             float* __restrict__ Wc, float* __restrict__ bc) {
    int tid = threadIdx.x;
    if (tid == 0) {
        int run = 0;
        for (int i = 0; i < nB; ++i) {
            int t = bsums[i];
            bsums[i] = run;
            run += t;
        }
    } else if (tid >= 64 && tid < 64 + 192) {
        int i = tid - 64;
        int k = i / 3, j = i % 3;
        float acc = 0.f;
#pragma unroll
        for (int c = 0; c < 64; ++c) acc = fmaf(W2[k * 64 + c], Wl[c * 3 + j], acc);
        Wc[k * 3 + j] = acc;
    } else if (tid >= 1 && tid <= 3) {
        int j = tid - 1;
        float acc = bl[j];
#pragma unroll
        for (int c = 0; c < 64; ++c) acc = fmaf(b2[c], Wl[c * 3 + j], acc);
        bc[j] = acc;
    }
}

// ---- pass 1c: partition edges into buckets via LDS cursors ----
__global__ void k_partition(const int* __restrict__ src, const int* __restrict__ dst,
                            const int* __restrict__ scanned, const int* __restrict__ bsums,
                            u32* __restrict__ staged, int nE, int NBUCK) {
    __shared__ int cur[512];
    int tid = threadIdx.x;
    for (int k = tid; k < NBUCK; k += 256) {
        int idx = k * NB1 + blockIdx.x;
        cur[k] = scanned[idx] + bsums[idx >> 12];
    }
    __syncthreads();
    int i = blockIdx.x * 256 + tid, stride = NB1 * 256;
    for (; i < nE; i += stride) {
        int d = dst[i];
        int k = d >> 8;
        int pos = atomicAdd(&cur[k], 1);
        staged[pos] = (u32)src[i] | ((u32)(d & 255) << 20);
    }
}

// ---- pass 2: per-bucket LDS count+scan+place -> esrc, rowptr, dinv ----
__global__ void k_pass2(const u32* __restrict__ staged, const int* __restrict__ scanned,
                        const int* __restrict__ bsums,
                        float* __restrict__ dinv, int* __restrict__ rowptr,
                        int* __restrict__ esrc, int nN, int nE, int NBUCK) {
    __shared__ int cnt[256], cur[256], sh[256];
    int bk = blockIdx.x, tid = threadIdx.x;
    int i0 = bk * NB1;
    int base = scanned[i0] + bsums[i0 >> 12];
    int end = nE;
    if (bk + 1 < NBUCK) {
        int i1 = (bk + 1) * NB1;
        end = scanned[i1] + bsums[i1 >> 12];
    }
    cnt[tid] = 0;
    __syncthreads();
    for (int e = base + tid; e < end; e += 256) atomicAdd(&cnt[staged[e] >> 20], 1);
    __syncthreads();
    int v = cnt[tid];
    sh[tid] = v;
    __syncthreads();
    for (int off = 1; off < 256; off <<= 1) {
        int t = (tid >= off) ? sh[tid - off] : 0;
        __syncthreads();
        sh[tid] += t;
        __syncthreads();
    }
    int excl = sh[tid] - v;
    int node = bk * 256 + tid;
    if (node < nN) {
        rowptr[node] = base + excl;
        dinv[node] = rsqrtf(1.0f + (float)v);
    }
    cur[tid] = excl;
    __syncthreads();
    for (int e = base + tid; e < end; e += 256) {
        u32 r = staged[e];
        int j = r >> 20;
        int pos = atomicAdd(&cur[j], 1);
        esrc[base + pos] = (int)(r & 0xFFFFFu);
    }
    if (bk == 0 && tid == 0) rowptr[nN] = nE;
}

// ---- fused gather of prescaled bf16 rows + self + (bias,relu,outscale) ----
__global__ void k_gather_bf(const int* __restrict__ rowptr, const int* __restrict__ esrc,
                            const uint2* __restrict__ H, const float* __restrict__ dinv,
                            const float* __restrict__ bias, uint2* __restrict__ Obf,
                            float4* __restrict__ Of, int nN, int relu, int addb, int outbf) {
    int node = blockIdx.x * 16 + (threadIdx.x >> 4);
    int lane = threadIdx.x & 15;
    if (node >= nN) return;
    int e0 = rowptr[node], e1 = rowptr[node + 1];
    float4 acc = make_float4(0.f, 0.f, 0.f, 0.f);
#define GSTEP(s) { uint2 v = H[(size_t)(s) * 16 + lane]; \
        acc.x += bflo(v.x); acc.y += bfhi(v.x); \
        acc.z += bflo(v.y); acc.w += bfhi(v.y); }
    int e = e0;
    for (; e + 3 < e1; e += 4) {
        int s0 = esrc[e], s1 = esrc[e + 1], s2 = esrc[e + 2], s3 = esrc[e + 3];
        GSTEP(s0) GSTEP(s1) GSTEP(s2) GSTEP(s3)
    }
    for (; e < e1; ++e) {
        int s = esrc[e];
        GSTEP(s)
    }
#undef GSTEP
    float di = dinv[node];
    uint2 hv = H[(size_t)node * 16 + lane];
    float x0 = di * (acc.x + bflo(hv.x));
    float x1 = di * (acc.y + bfhi(hv.x));
    float x2 = di * (acc.z + bflo(hv.y));
    float x3 = di * (acc.w + bfhi(hv.y));
    if (addb) {
        float4 bb = ((const float4*)bias)[lane];
        x0 += bb.x; x1 += bb.y; x2 += bb.z; x3 += bb.w;
    }
    if (relu) {
        x0 = fmaxf(x0, 0.f); x1 = fmaxf(x1, 0.f);
        x2 = fmaxf(x2, 0.f); x3 = fmaxf(x3, 0.f);
    }
    if (outbf) {
        Obf[(size_t)node * 16 + lane] =
            make_uint2(packbf(di * x0, di * x1), packbf(di * x2, di * x3));
    } else {
        Of[(size_t)node * 16 + lane] = make_float4(x0, x1, x2, x3);
    }
}

// ---- pool: CH=64 nodes/block; LDS batch; unrolled fast path for uniform chunks ----
__global__ void k_pool(const float* __restrict__ Y, const int* __restrict__ batch,
                       float* __restrict__ gsum, float* __restrict__ gcnt, int nN) {
    const int CH = 64;
    __shared__ int bsh[CH];
    __shared__ float red[4][64];
    int n0 = blockIdx.x * CH;
    int tid = threadIdx.x;
    int f = tid & 63, rl = tid >> 6;
    int nend = n0 + CH; if (nend > nN) nend = nN;
    int cnt = nend - n0;
    if (cnt <= 0) return;
    if (tid < CH) bsh[tid] = (n0 + tid < nN) ? batch[n0 + tid] : -1;
    __syncthreads();
    int g0 = bsh[0];
    bool uniform = (cnt == CH) && (bsh[CH - 1] == g0);
    if (uniform) {
        const float* Yp = Y + (size_t)n0 * 64 + f;
        float acc = 0.f;
#pragma unroll
        for (int r = 0; r < 16; ++r) acc += Yp[(size_t)(rl + r * 4) * 64];
        red[rl][f] = acc;
        __syncthreads();
        if (rl == 0) {
            float s = red[0][f] + red[1][f] + red[2][f] + red[3][f];
            unsafeAtomicAdd(&gsum[g0 * 64 + f], s);
        }
    } else {
        int curg = -1; float acc = 0.f;
        for (int n = n0 + rl; n < nend; n += 4) {
            int g = bsh[n - n0];
            if (g != curg) {
                if (curg >= 0) unsafeAtomicAdd(&gsum[curg * 64 + f], acc);
                curg = g; acc = 0.f;
            }
            acc += Y[(size_t)n * 64 + f];
        }
        if (curg >= 0) unsafeAtomicAdd(&gsum[curg * 64 + f], acc);
    }
    if (tid == 0) {
        int curg = bsh[0]; float c = 0.f;
        for (int i = 0; i < cnt; ++i) {
            if (bsh[i] != curg) {
                unsafeAtomicAdd(&gcnt[curg], c);
                curg = bsh[i]; c = 0.f;
            }
            c += 1.f;
        }
        unsafeAtomicAdd(&gcnt[curg], c);
    }
}

// ---- head: out[g] = softmax( mean_g @ Wc + bc ), Wc [64x3] ----
__global__ void k_head(const float* __restrict__ gsum, const float* __restrict__ gcnt,
                       const float* __restrict__ Wc, const float* __restrict__ bc,
                       float* __restrict__ out) {
    int g = threadIdx.x;
    if (g >= NGRAPH) return;
    float inv = 1.0f / fmaxf(gcnt[g], 1.0f);
    float l0 = bc[0], l1 = bc[1], l2 = bc[2];
#pragma unroll
    for (int k = 0; k < 64; ++k) {
        float m = gsum[g * 64 + k] * inv;
        l0 = fmaf(m, Wc[k * 3 + 0], l0);
        l1 = fmaf(m, Wc[k * 3 + 1], l1);
        l2 = fmaf(m, Wc[k * 3 + 2], l2);
    }
    float mx = fmaxf(l0, fmaxf(l1, l2));
    float e0 = expf(l0 - mx), e1 = expf(l1 - mx), e2 = expf(l2 - mx);
    float s = e0 + e1 + e2;
    out[g * 3 + 0] = e0 / s;
    out[g * 3 + 1] = e1 / s;
    out[g * 3 + 2] = e2 / s;
}

extern "C" void kernel_launch(void* const* d_in, const int* in_sizes, int n_in,
                              void* d_out, int out_size, void* d_ws, size_t ws_size,
                              hipStream_t stream) {
    const float* x     = (const float*)d_in[0];
    const int*   ei    = (const int*)d_in[1];
    const int*   batch = (const int*)d_in[2];
    const float* W1    = (const float*)d_in[3];
    const float* b1    = (const float*)d_in[4];
    const float* W2    = (const float*)d_in[5];
    const float* b2    = (const float*)d_in[6];
    const float* Wl    = (const float*)d_in[7];
    const float* bl    = (const float*)d_in[8];
    float* out = (float*)d_out;

    int nN = in_sizes[2];
    int nE = in_sizes[1] / 2;
    const int* srcp = ei;
    const int* dstp = ei + nE;

    int NBUCK = (nN + 255) >> 8;          // 391
    int L = NBUCK * NB1;                   // 100096
    int nB = (L + SCAN_B - 1) / SCAN_B;    // 25

    char* ws = (char*)d_ws;
    size_t off = 0;
    auto alloc = [&](size_t bytes) -> void* {
        void* p = ws + off;
        off += (bytes + 255) & ~(size_t)255;
        return p;
    };
    float* dinv    = (float*)alloc((size_t)nN * 4);
    int*   rowptr  = (int*)alloc(((size_t)nN + 1) * 4);
    int*   hist    = (int*)alloc((size_t)L * 4);
    int*   scanned = (int*)alloc((size_t)L * 4);
    int*   bsums   = (int*)alloc(256 * 4);
    u32*   staged  = (u32*)alloc((size_t)nE * 4);
    int*   esrc    = (int*)alloc((size_t)nE * 4);
    u32*   Hbf     = (u32*)alloc((size_t)nN * 32 * 4);   // bf16-packed [nN][64]
    u32*   Ybf     = (u32*)alloc((size_t)nN * 32 * 4);
    float* Z       = (float*)alloc((size_t)nN * 64 * 4);
    float* gsum    = (float*)alloc(NGRAPH * 64 * 4);     // gcnt directly follows
    float* gcnt    = (float*)alloc(NGRAPH * 4);
    float* Wc      = (float*)alloc(64 * 3 * 4);
    float* bc      = (float*)alloc(3 * 4);

    // atomic-free CSR first (produces dinv for the prescaled GEMM);
    // k_hist block 0 zeroes gsum+gcnt (4160 floats, contiguous)
    k_hist<<<NB1, 256, 0, stream>>>(dstp, hist, gsum, NGRAPH * 64 + NGRAPH, nE, NBUCK);
    k_scanA<<<nB, SCAN_T, 0, stream>>>(hist, scanned, bsums, L);
    k_scanB_fold<<<1, 256, 0, stream>>>(bsums, nB, W2, b2, Wl, bl, Wc, bc);
    k_partition<<<NB1, 256, 0, stream>>>(srcp, dstp, scanned, bsums, staged, nE, NBUCK);
    k_pass2<<<NBUCK, 256, 0, stream>>>(staged, scanned, bsums, dinv, rowptr, esrc, nN, nE, NBUCK);

    // hs = dinv * (x@W1), bf16 rows
    k_gemm_reg<<<1024, 256, 0, stream>>>(x, W1, dinv, Hbf, nN);

    // layer 1: ys1 = dinv * relu(gather(hs)+b1) -> Ybf (bf16)
    k_gather_bf<<<(nN + 15) / 16, 256, 0, stream>>>(
        rowptr, esrc, (const uint2*)Hbf, dinv, b1, (uint2*)Ybf, nullptr, nN, 1, 1, 1);
    // layer 2: z = dinv*(gather(ys1)+self) -> Z (fp32); W2/b2 folded into head
    k_gather_bf<<<(nN + 15) / 16, 256, 0, stream>>>(
        rowptr, esrc, (const uint2*)Ybf, dinv, nullptr, nullptr, (float4*)Z, nN, 0, 0, 0);

    // pool z + folded head
    k_pool<<<(nN + 63) / 64, 256, 0, stream>>>(Z, batch, gsum, gcnt, nN);
    k_head<<<1, 64, 0, stream>>>(gsum, gcnt, Wc, bc, out);
}